// Round 9
// baseline (292.811 us; speedup 1.0000x reference)
//
#include <hip/hip_runtime.h>

typedef unsigned int u32;
typedef unsigned short u16;
typedef unsigned long long ull;

constexpr int kB = 16, kT = 16, kN = 184, kD = 128, kH = 8, kHD = 16;
constexpr int kBT = kB * kT;            // 256
constexpr int kRows = kBT * kN;         // 47104
constexpr int kTile = kN * kHD;         // 2944 elements per (hb,t) tile
// softmax scale folded into q at projection: 0.25 * log2(e)
#define KQSCALE 0.36067376022224085f

typedef __attribute__((ext_vector_type(8))) short bf16x8;
typedef __attribute__((ext_vector_type(4))) float f32x4;

union FragU {
  bf16x8 f;
  ull u[2];
  uint4 q;
  u16 h[8];
};

#define MFMA(a, b, c) __builtin_amdgcn_mfma_f32_16x16x32_bf16((a), (b), (c), 0, 0, 0)

__device__ __forceinline__ float bf2f(u16 v) {
  return __uint_as_float(((u32)v) << 16);
}
__device__ __forceinline__ u16 f2bf(float f) {
  u32 x = __float_as_uint(f);
  x += 0x7fffu + ((x >> 16) & 1u);   // RNE
  return (u16)(x >> 16);
}
// pack two fp32 -> two bf16 (RNE) in one u32: lo in [15:0], hi in [31:16]
__device__ __forceinline__ u32 pack_bf2(float lo, float hi) {
  u32 a = __float_as_uint(lo); a += 0x7fffu + ((a >> 16) & 1u);
  u32 b = __float_as_uint(hi); b += 0x7fffu + ((b >> 16) & 1u);
  return __builtin_amdgcn_perm(b, a, 0x07060302);
}
// pack two fp32 -> two bf16 (truncate) in one u32 — single v_perm
__device__ __forceinline__ u32 pack_trunc(float lo, float hi) {
  return __builtin_amdgcn_perm(__float_as_uint(hi), __float_as_uint(lo), 0x07060302);
}
__device__ __forceinline__ u16 trunc_bf(float f) {
  return (u16)(__float_as_uint(f) >> 16);
}

// ---------------------------------------------------------------------------
// Kernel 1: adp softmax fragments (standalone again — proj no longer exists).
// Grid 12; phase 1 redundant per block, phase 2 block-strided.
// ---------------------------------------------------------------------------
__global__ __launch_bounds__(256) void adp_kernel(
    const float* __restrict__ ne1, const float* __restrict__ ne2,
    u16* __restrict__ arr3, u16* __restrict__ arr4) {
  __shared__ float s1[kN * 10];
  __shared__ float s2[10 * kN];
  __shared__ float l1r[kN];
  __shared__ float l2c[kN];
  const int tid = threadIdx.x;
  for (int i = tid; i < kN * 10; i += 256) { s1[i] = ne1[i]; s2[i] = ne2[i]; }
  __syncthreads();

  if (tid < kN) {
    const int r = tid;
    float reg[10];
#pragma unroll
    for (int e = 0; e < 10; ++e) reg[e] = s1[r * 10 + e];
    float sum = 0.f;
    for (int c = 0; c < kN; ++c) {
      float d = 0.f;
#pragma unroll
      for (int e = 0; e < 10; ++e) d += reg[e] * s2[e * kN + c];
      sum += __expf(d);
    }
    l1r[r] = sum;

    const int c = tid;
    float regc[10];
#pragma unroll
    for (int e = 0; e < 10; ++e) regc[e] = s2[e * kN + c];
    sum = 0.f;
    for (int r2 = 0; r2 < kN; ++r2) {
      float d = 0.f;
#pragma unroll
      for (int e = 0; e < 10; ++e) d += s1[r2 * 10 + e] * regc[e];
      sum += __expf(d);
    }
    l2c[c] = sum;
  }
  __syncthreads();

  for (int ee = blockIdx.x * 256 + tid; ee < 12 * 6 * 64; ee += 12 * 256) {
    const int i = ee / 384;
    const int rem = ee - i * 384;
    const int p = rem >> 6;
    const int lane = rem & 63;
    const int row = i * 16 + (lane & 15);
    const int cb = p * 32 + (lane >> 4) * 8;
    FragU fo3, fo4;
    const bool rok = row < kN;
    float inv1 = 0.f, inv2 = 0.f;
    float rreg[10], creg[10];
    if (rok) {
      inv1 = 1.f / l1r[row];
      inv2 = 1.f / l2c[row];
#pragma unroll
      for (int e = 0; e < 10; ++e) {
        rreg[e] = s1[row * 10 + e];
        creg[e] = s2[e * kN + row];
      }
    }
#pragma unroll
    for (int j = 0; j < 8; ++j) {
      const int col = cb + j;
      float v3 = 0.f, v4 = 0.f;
      if (rok && col < kN) {
        float d3 = 0.f, d4 = 0.f;
#pragma unroll
        for (int e = 0; e < 10; ++e) {
          d3 += rreg[e] * s2[e * kN + col];
          d4 += s1[col * 10 + e] * creg[e];
        }
        v3 = __expf(d3) * inv1;
        v4 = __expf(d4) * inv2;
      }
      fo3.h[j] = f2bf(v3);
      fo4.h[j] = f2bf(v4);
    }
    *(uint4*)(arr3 + (size_t)ee * 8) = fo3.q;
    *(uint4*)(arr4 + (size_t)ee * 8) = fo4.q;
  }
}

// ---------------------------------------------------------------------------
// Kernel 2 (r16): FUSED projection + dual-softmax attention + adp + Wm.
// Block (h,bt) computes its own q/k/v[184x16] head-slice via MFMA (36/wave,
// zero compute redundancy — each block does only its head's 16 W-columns),
// stages them into LDS tiles aliased over the ET0 region, then runs the r11
// attention body unchanged. proj kernel + 36 MB HBM write + 36 MB read and
// the mg/qg alias constraint are all eliminated.
//  * block swizzle h = bx&7, bt = bx>>3: 8 heads of a bt co-resident ->
//    fp32 input re-reads are L2-hot (283 KB/bt, ~2.2 MB/XCD working set).
//  * proj MFMA mapping = r6-verified: B-frag lane m = W row (output col),
//    D row = quad*4+r, D col = m. bias from b*[h*16+m]; q pre-scaled.
//  * s_q/s_k [192][24] u16 (16B-aligned b128 rows); s_vT [16][200] with pad
//    tokens 184..191 explicitly zeroed (preserves the l1-8 / l2-8 pad
//    invariants: zeroed kfr/qB pad rows -> S=0 -> E=1, vT pad = 0).
//  * staging lives in [13824, 26240) u16 (inside ET0 region): seq =
//    stage | bar | frag reads to regs | bar | S0 overwrites ET0. LDS still
//    78,848 B -> 2 blocks/CU; VGPR cap 256 (no spill risk).
// ---------------------------------------------------------------------------
__global__ __launch_bounds__(256, 2) void attn_kernel(
    const float* __restrict__ qin, const float* __restrict__ kin, const float* __restrict__ vin,
    const float* __restrict__ Wq, const float* __restrict__ Wk, const float* __restrict__ Wv,
    const float* __restrict__ bq, const float* __restrict__ bk, const float* __restrict__ bv,
    const u16* __restrict__ arr3, const u16* __restrict__ arr4,
    const float* __restrict__ Wm, const float* __restrict__ bm,
    u16* __restrict__ mg) {
  __shared__ u16 pool[39424];              // 78,848 B
  u16* const s_E   = pool;                 // [192][72]  (13824 elems)
  u16* const s_ET0 = pool + 13824;         // [64][200]  (12800 elems)
  u16* const s_ET1 = pool + 26624;         // [64][200]  (12800 elems)
  u16* const s_q   = pool + 13824;         // alias ET0: [192][24] (4608)
  u16* const s_k   = pool + 18432;         // alias ET0: [192][24] (4608)
  u16* const s_vT  = pool + 23040;         // alias ET0: [16][200] (3200)
  u16* const s_cat = s_ET1;                // alias: 4*1152 = 4608 elems

  const int tid = threadIdx.x;
  const int h  = blockIdx.x & 7;           // bt-major swizzle for L2 reuse
  const int bt = blockIdx.x >> 3;
  const size_t base = (size_t)(h * kBT + bt) * kTile;
  const int w = tid >> 6, lane = tid & 63;
  const int quad = lane >> 4, m = lane & 15;
  const f32x4 zero4 = {0.f, 0.f, 0.f, 0.f};

  // ================= fused projection staging =================
  // wave w computes tiles t = w, w+4, w+8 of each tensor (n0 = t*16).
#pragma unroll
  for (int u = 0; u < 3; ++u) {
    const float* in  = (u == 0) ? qin : (u == 1) ? kin : vin;
    const float* Wt  = (u == 0) ? Wq  : (u == 1) ? Wk  : Wv;
    const float* bs  = (u == 0) ? bq  : (u == 1) ? bk  : bv;
    // W B-frags (lane m = W row h*16+m = output col; quad*8+kp*32 = d)
    bf16x8 wf[4];
#pragma unroll
    for (int kp = 0; kp < 4; ++kp) {
      const float* wp = Wt + (size_t)(h * 16 + m) * 128 + kp * 32 + quad * 8;
      const float4 wa = *(const float4*)wp;
      const float4 wb2 = *(const float4*)(wp + 4);
      FragU f;
      f.q = make_uint4(pack_bf2(wa.x, wa.y), pack_bf2(wa.z, wa.w),
                       pack_bf2(wb2.x, wb2.y), pack_bf2(wb2.z, wb2.w));
      wf[kp] = f.f;
    }
    const float bias = bs[h * 16 + m];
#pragma unroll
    for (int ti = 0; ti < 3; ++ti) {
      const int n0 = (w + ti * 4) * 16;
      f32x4 acc = zero4;
#pragma unroll
      for (int kp = 0; kp < 4; ++kp) {
        FragU a; a.u[0] = 0; a.u[1] = 0;
        const int row = n0 + m;            // A row = input token
        if (row < kN) {
          const float* ap = in + ((size_t)bt * kN + row) * 128 + kp * 32 + quad * 8;
          const float4 xa = *(const float4*)ap;
          const float4 xb = *(const float4*)(ap + 4);
          a.q = make_uint4(pack_bf2(xa.x, xa.y), pack_bf2(xa.z, xa.w),
                           pack_bf2(xb.x, xb.y), pack_bf2(xb.z, xb.w));
        }
        acc = MFMA(a.f, wf[kp], acc);
      }
      // D: lane(m = col c', quad), reg r -> token n0 + quad*4 + r
      if (u == 0) {
#pragma unroll
        for (int r = 0; r < 4; ++r)
          s_q[(n0 + quad * 4 + r) * 24 + m] = f2bf((acc[r] + bias) * KQSCALE);
      } else if (u == 1) {
#pragma unroll
        for (int r = 0; r < 4; ++r)
          s_k[(n0 + quad * 4 + r) * 24 + m] = f2bf(acc[r] + bias);
      } else {
        const int tb = n0 + quad * 4;
        const float v0 = (tb + 0 < kN) ? acc[0] + bias : 0.f;
        const float v1 = (tb + 1 < kN) ? acc[1] + bias : 0.f;
        const float v2 = (tb + 2 < kN) ? acc[2] + bias : 0.f;
        const float v3 = (tb + 3 < kN) ? acc[3] + bias : 0.f;
        uint2 pv;
        pv.x = pack_bf2(v0, v1);
        pv.y = pack_bf2(v2, v3);
        *(uint2*)(s_vT + m * 200 + tb) = pv;   // vT[ch=m][tok tb..tb+3]
      }
    }
  }

  // ---- Wm A-fragments with interleaved cat-dim mapping (unchanged).
  bf16x8 wmb[2];
#pragma unroll
  for (int kt = 0; kt < 2; ++kt) {
    FragU f;
#pragma unroll
    for (int j = 0; j < 8; ++j) {
      const int kdl = quad * 8 + j;
      const int orig = (kt * 2 + (kdl & 1)) * 16 + (kdl >> 1);
      f.h[j] = f2bf(Wm[m * 64 + orig]);
    }
    wmb[kt] = f.f;
  }
  const float4 bm4 = *(const float4*)(bm + quad * 4);

  __syncthreads();   // bar_a: staged q/k/vT visible to all waves

  // ---- K A-frags + Q B-frags from LDS tiles (cross-wave reads).
  bf16x8 kfr[12];
#pragma unroll
  for (int t12 = 0; t12 < 12; ++t12) {
    FragU fk; fk.u[0] = 0; fk.u[1] = 0;
    const int tok = t12 * 16 + m;
    if (quad < 2 && tok < kN)
      fk.q = *(const uint4*)(s_k + tok * 24 + quad * 8);
    kfr[t12] = fk.f;
  }
  bf16x8 qB[3];
#pragma unroll
  for (int ti = 0; ti < 3; ++ti) {
    FragU fq; fq.u[0] = 0; fq.u[1] = 0;
    const int tok = (w + ti * 4) * 16 + m;
    if (quad < 2 && tok < kN)
      fq.q = *(const uint4*)(s_q + tok * 24 + quad * 8);
    qB[ti] = fq.f;
  }
  bf16x8 vb[6];   // V B-frags: B[token][ch]
#pragma unroll
  for (int p = 0; p < 6; ++p) {
    FragU f;
    f.q = *(const uint4*)(s_vT + m * 200 + p * 32 + quad * 8);
    vb[p] = f.f;
  }

  __syncthreads();   // bar_a2: all frag reads done before S0 overwrites ET0

  FragU onesU; onesU.u[0] = 0x3F803F803F803F80ULL; onesU.u[1] = onesU.u[0];
  const bf16x8 ones = onesU.f;

  f32x4 o1[3], l1[3], o3[3], o4[3], o2[3], l2[3];
#pragma unroll
  for (int ti = 0; ti < 3; ++ti) {
    o1[ti] = zero4; l1[ti] = zero4; o3[ti] = zero4;
    o4[ti] = zero4; o2[ti] = zero4; l2[ti] = zero4;
  }

  // S_PHASE(CC, ETB): wave computes its 3 q-tiles x 4 k-tiles of E = exp2(S),
  // stores as b64 into s_E rows (own rows, wave-local) + b16 scatter into ETB.
#define S_PHASE(CC, ETB)                                                      \
  do {                                                                        \
    _Pragma("unroll") for (int ti = 0; ti < 3; ++ti) {                        \
      const int qt = w + ti * 4;                                              \
      const int qrow = qt * 16 + m;                                           \
      _Pragma("unroll") for (int ktl = 0; ktl < 4; ++ktl) {                   \
        f32x4 sv = MFMA(kfr[(CC) * 4 + ktl], qB[ti], zero4);                  \
        const float e0 = exp2f(sv[0]), e1 = exp2f(sv[1]);                     \
        const float e2 = exp2f(sv[2]), e3 = exp2f(sv[3]);                     \
        uint2 ev;                                                             \
        ev.x = pack_trunc(e0, e1);                                            \
        ev.y = pack_trunc(e2, e3);                                            \
        *(uint2*)(s_E + qrow * 72 + ktl * 16 + quad * 4) = ev;                \
        u16* etp = (ETB) + (ktl * 16 + quad * 4) * 200 + qrow;                \
        etp[0]   = trunc_bf(e0);                                              \
        etp[200] = trunc_bf(e1);                                              \
        etp[400] = trunc_bf(e2);                                              \
        etp[600] = trunc_bf(e3);                                              \
      }                                                                       \
    }                                                                         \
  } while (0)

#define LOAD_ARR(CC)                                                          \
  _Pragma("unroll") for (int ti = 0; ti < 3; ++ti) {                          \
    const int qt = w + ti * 4;                                                \
    _Pragma("unroll") for (int pl = 0; pl < 2; ++pl) {                        \
      const int pg = (CC) * 2 + pl;                                           \
      a3f[ti * 2 + pl].q = *(const uint4*)(arr3 + (size_t)((qt * 6 + pg) * 64 + lane) * 8); \
      a4f[ti * 2 + pl].q = *(const uint4*)(arr4 + (size_t)((qt * 6 + pg) * 64 + lane) * 8); \
    }                                                                         \
  }

  // ROW_PHASE(CC): reads own s_E rows (wave-local; no barrier dependency).
#define ROW_PHASE(CC)                                                         \
  _Pragma("unroll") for (int ti = 0; ti < 3; ++ti) {                          \
    const int qt = w + ti * 4;                                                \
    const u16* erp = s_E + (qt * 16 + m) * 72 + quad * 8;                     \
    _Pragma("unroll") for (int pl = 0; pl < 2; ++pl) {                        \
      const int pg = (CC) * 2 + pl;                                           \
      FragU pa; pa.q = *(const uint4*)(erp + pl * 32);                        \
      o1[ti] = MFMA(pa.f, vb[pg], o1[ti]);                                    \
      l1[ti] = MFMA(pa.f, ones, l1[ti]);                                      \
      o3[ti] = MFMA(a3f[ti * 2 + pl].f, vb[pg], o3[ti]);                      \
      o4[ti] = MFMA(a4f[ti * 2 + pl].f, vb[pg], o4[ti]);                      \
    }                                                                         \
  }

  // COL_PHASE(CC, ETB): reads E^T rows (cross-wave; requires barrier).
#define COL_PHASE(CC, ETB)                                                    \
  {                                                                           \
    const u16* etr = (ETB) + (w * 16 + m) * 200 + quad * 8;                   \
    _Pragma("unroll") for (int pg = 0; pg < 6; ++pg) {                        \
      FragU pT; pT.q = *(const uint4*)(etr + pg * 32);                        \
      o2[CC] = MFMA(pT.f, vb[pg], o2[CC]);                                    \
      l2[CC] = MFMA(pT.f, ones, l2[CC]);                                      \
    }                                                                         \
  }

  // ---- I0: produce chunk 0
  S_PHASE(0, s_ET0);
  __syncthreads();   // bar1: ET0 sealed
  // ---- I1: consume chunk 0, produce chunk 1 (ROW reads s_E BEFORE S
  //          overwrites — WAR order)
  {
    FragU a3f[6], a4f[6];
    LOAD_ARR(0);
    COL_PHASE(0, s_ET0);
    ROW_PHASE(0);
    S_PHASE(1, s_ET1);
  }
  __syncthreads();   // bar2: ET1 sealed; COL0 done with ET0
  // ---- I2
  {
    FragU a3f[6], a4f[6];
    LOAD_ARR(1);
    COL_PHASE(1, s_ET1);
    ROW_PHASE(1);
    S_PHASE(2, s_ET0);
  }
  __syncthreads();   // bar3: ET0 sealed; COL1 done with ET1 (cat may reuse)
  // ---- I3
  {
    FragU a3f[6], a4f[6];
    LOAD_ARR(2);
    COL_PHASE(2, s_ET0);
    ROW_PHASE(2);
  }

#undef S_PHASE
#undef LOAD_ARR
#undef ROW_PHASE
#undef COL_PHASE

  // ================= fused Wm epilogue (per own tile) =================
  u16* cw = s_cat + w * 1152;
#pragma unroll
  for (int ti = 0; ti < 3; ++ti) {
    const int tt = w + ti * 4;
#pragma unroll
    for (int r = 0; r < 4; ++r) {
      const int token = quad * 4 + r;
      const float n1 = o1[ti][r] * __builtin_amdgcn_rcpf(l1[ti][r] - 8.0f);
      const float n2 = o2[ti][r] * __builtin_amdgcn_rcpf(l2[ti][r] - 8.0f);
      *(u32*)(cw + token * 72 + 2 * m)      = pack_bf2(n1, n2);       // dims 2m,2m+1
      *(u32*)(cw + token * 72 + 32 + 2 * m) = pack_bf2(o3[ti][r], o4[ti][r]);
    }
    f32x4 macc = {bm4.x, bm4.y, bm4.z, bm4.w};
#pragma unroll
    for (int kt = 0; kt < 2; ++kt) {
      FragU ca; ca.q = *(const uint4*)(cw + m * 72 + kt * 32 + quad * 8);
      macc = MFMA(wmb[kt], ca.f, macc);   // filt^T = Wm @ cat^T
    }
    if (tt * 16 + m < kN) {
      *(uint2*)(mg + base + (tt * 16 + m) * 16 + quad * 4) =
          make_uint2(pack_bf2(macc[0], macc[1]), pack_bf2(macc[2], macc[3]));
    }
  }
}

// ---------------------------------------------------------------------------
// Kernel 3: MFMA head-merge + Wo GEMM, fp32 out + bo (r15 version: Wo staged
// from fp32 with inline RNE conversion).
// ---------------------------------------------------------------------------
__global__ __launch_bounds__(256) void out_kernel(
    const u16* __restrict__ mg, const float* __restrict__ Wo,
    const float* __restrict__ bo, float* __restrict__ outg) {
  __shared__ u16 s_w[128 * 136];
  const int tid = threadIdx.x;
  {
    for (int i = tid; i < 2048; i += 256) {
      const int row = i >> 4, c8 = (i & 15) * 8;
      const float4 w0 = *(const float4*)(Wo + row * 128 + c8);
      const float4 w1 = *(const float4*)(Wo + row * 128 + c8 + 4);
      *(uint4*)(s_w + row * 136 + c8) =
          make_uint4(pack_bf2(w0.x, w0.y), pack_bf2(w0.z, w0.w),
                     pack_bf2(w1.x, w1.y), pack_bf2(w1.z, w1.w));
    }
  }
  __syncthreads();

  const int w = tid >> 6, lane = tid & 63, quad = lane >> 4, m = lane & 15;
  const int r0 = blockIdx.x * 128;

  f32x4 acc0[8], acc1[8];
  const f32x4 z4 = {0.f, 0.f, 0.f, 0.f};
#pragma unroll
  for (int ct = 0; ct < 8; ++ct) { acc0[ct] = z4; acc1[ct] = z4; }

  const int hh = quad >> 1, hd8 = (quad & 1) * 8;
  const int ra = r0 + w * 16 + m;
  const int bt0 = ra / kN, n0 = ra - bt0 * kN;
  const int rb = ra + 64;
  const int bt1 = rb / kN, n1 = rb - bt1 * kN;
  const u16* mp0 = mg + ((size_t)(hh * kBT + bt0) * kN + n0) * 16 + hd8;
  const u16* mp1 = mg + ((size_t)(hh * kBT + bt1) * kN + n1) * 16 + hd8;
  const size_t hstep = (size_t)2 * kBT * kN * 16;

#pragma unroll
  for (int kp = 0; kp < 4; ++kp) {
    FragU a0; a0.q = *(const uint4*)(mp0 + kp * hstep);
    FragU a1; a1.q = *(const uint4*)(mp1 + kp * hstep);
#pragma unroll
    for (int ct = 0; ct < 8; ++ct) {
      FragU bfr; bfr.q = *(const uint4*)(s_w + (ct * 16 + m) * 136 + kp * 32 + quad * 8);
      acc0[ct] = MFMA(a0.f, bfr.f, acc0[ct]);
      acc1[ct] = MFMA(a1.f, bfr.f, acc1[ct]);
    }
  }

  float bc[8];
#pragma unroll
  for (int ct = 0; ct < 8; ++ct) bc[ct] = bo[ct * 16 + m];

#pragma unroll
  for (int half = 0; half < 2; ++half) {
    const f32x4* acc = half ? acc1 : acc0;
    const int rbase = r0 + (w + half * 4) * 16 + quad * 4;
#pragma unroll
    for (int rr = 0; rr < 4; ++rr) {
      float* op = outg + (size_t)(rbase + rr) * 128 + m;
#pragma unroll
      for (int ct = 0; ct < 8; ++ct)
        op[ct * 16] = acc[ct][rr] + bc[ct];
    }
  }
}

// ---------------------------------------------------------------------------
extern "C" void kernel_launch(void* const* d_in, const int* in_sizes, int n_in,
                              void* d_out, int out_size, void* d_ws, size_t ws_size,
                              hipStream_t stream) {
  const float* query = (const float*)d_in[0];
  const float* key   = (const float*)d_in[1];
  const float* value = (const float*)d_in[2];
  const float* Wq = (const float*)d_in[3];
  const float* bq = (const float*)d_in[4];
  const float* Wk = (const float*)d_in[5];
  const float* bk = (const float*)d_in[6];
  const float* Wv = (const float*)d_in[7];
  const float* bv = (const float*)d_in[8];
  const float* Wm = (const float*)d_in[9];
  const float* bm = (const float*)d_in[10];
  const float* Wo = (const float*)d_in[11];
  const float* bo = (const float*)d_in[12];
  const float* ne1 = (const float*)d_in[13];
  const float* ne2 = (const float*)d_in[14];

  const size_t tensor_bytes = (size_t)kH * kB * kT * kN * kHD * 2;  // 12,058,624
  const size_t frag_bytes = (size_t)12 * 6 * 64 * 8 * 2;            // 73,728
  char* ws = (char*)d_ws;
  u16* mgs  = (u16*)(ws);                        // attn output m (bf16)
  u16* arr3 = (u16*)(ws + tensor_bytes);
  u16* arr4 = (u16*)(ws + tensor_bytes + frag_bytes);

  adp_kernel<<<12, 256, 0, stream>>>(ne1, ne2, arr3, arr4);
  attn_kernel<<<kH * kB * kT, 256, 0, stream>>>(
      query, key, value, Wq, Wk, Wv, bq, bk, bv, arr3, arr4, Wm, bm, mgs);
  out_kernel<<<kRows / 128, 256, 0, stream>>>(mgs, Wo, bo, (float*)d_out);
}

// Round 10
// 292.085 us; speedup vs baseline: 1.0025x; 1.0025x over previous
//
#include <hip/hip_runtime.h>

typedef unsigned int u32;
typedef unsigned short u16;
typedef unsigned long long ull;

constexpr int kB = 16, kT = 16, kN = 184, kD = 128, kH = 8, kHD = 16;
constexpr int kBT = kB * kT;            // 256
constexpr int kRows = kBT * kN;         // 47104
constexpr int kTile = kN * kHD;         // 2944 elements per (hb,t) tile
// softmax scale folded into q at projection: 0.25 * log2(e)
#define KQSCALE 0.36067376022224085f

typedef __attribute__((ext_vector_type(8))) short bf16x8;
typedef __attribute__((ext_vector_type(4))) float f32x4;

union FragU {
  bf16x8 f;
  ull u[2];
  uint4 q;
  u16 h[8];
};

#define MFMA(a, b, c) __builtin_amdgcn_mfma_f32_16x16x32_bf16((a), (b), (c), 0, 0, 0)

__device__ __forceinline__ float bf2f(u16 v) {
  return __uint_as_float(((u32)v) << 16);
}
__device__ __forceinline__ u16 f2bf(float f) {
  u32 x = __float_as_uint(f);
  x += 0x7fffu + ((x >> 16) & 1u);   // RNE
  return (u16)(x >> 16);
}
// pack two fp32 -> two bf16 (RNE) in one u32: lo in [15:0], hi in [31:16]
__device__ __forceinline__ u32 pack_bf2(float lo, float hi) {
  u32 a = __float_as_uint(lo); a += 0x7fffu + ((a >> 16) & 1u);
  u32 b = __float_as_uint(hi); b += 0x7fffu + ((b >> 16) & 1u);
  return __builtin_amdgcn_perm(b, a, 0x07060302);
}
// pack two fp32 -> two bf16 (truncate) in one u32 — single v_perm
__device__ __forceinline__ u32 pack_trunc(float lo, float hi) {
  return __builtin_amdgcn_perm(__float_as_uint(hi), __float_as_uint(lo), 0x07060302);
}
__device__ __forceinline__ u16 trunc_bf(float f) {
  return (u16)(__float_as_uint(f) >> 16);
}

// ---------------------------------------------------------------------------
// Kernel 1: adp softmax fragments. Grid 12; phase 1 redundant per block,
// phase 2 block-strided.
// ---------------------------------------------------------------------------
__global__ __launch_bounds__(256) void adp_kernel(
    const float* __restrict__ ne1, const float* __restrict__ ne2,
    u16* __restrict__ arr3, u16* __restrict__ arr4) {
  __shared__ float s1[kN * 10];
  __shared__ float s2[10 * kN];
  __shared__ float l1r[kN];
  __shared__ float l2c[kN];
  const int tid = threadIdx.x;
  for (int i = tid; i < kN * 10; i += 256) { s1[i] = ne1[i]; s2[i] = ne2[i]; }
  __syncthreads();

  if (tid < kN) {
    const int r = tid;
    float reg[10];
#pragma unroll
    for (int e = 0; e < 10; ++e) reg[e] = s1[r * 10 + e];
    float sum = 0.f;
    for (int c = 0; c < kN; ++c) {
      float d = 0.f;
#pragma unroll
      for (int e = 0; e < 10; ++e) d += reg[e] * s2[e * kN + c];
      sum += __expf(d);
    }
    l1r[r] = sum;

    const int c = tid;
    float regc[10];
#pragma unroll
    for (int e = 0; e < 10; ++e) regc[e] = s2[e * kN + c];
    sum = 0.f;
    for (int r2 = 0; r2 < kN; ++r2) {
      float d = 0.f;
#pragma unroll
      for (int e = 0; e < 10; ++e) d += s1[r2 * 10 + e] * regc[e];
      sum += __expf(d);
    }
    l2c[c] = sum;
  }
  __syncthreads();

  for (int ee = blockIdx.x * 256 + tid; ee < 12 * 6 * 64; ee += 12 * 256) {
    const int i = ee / 384;
    const int rem = ee - i * 384;
    const int p = rem >> 6;
    const int lane = rem & 63;
    const int row = i * 16 + (lane & 15);
    const int cb = p * 32 + (lane >> 4) * 8;
    FragU fo3, fo4;
    const bool rok = row < kN;
    float inv1 = 0.f, inv2 = 0.f;
    float rreg[10], creg[10];
    if (rok) {
      inv1 = 1.f / l1r[row];
      inv2 = 1.f / l2c[row];
#pragma unroll
      for (int e = 0; e < 10; ++e) {
        rreg[e] = s1[row * 10 + e];
        creg[e] = s2[e * kN + row];
      }
    }
#pragma unroll
    for (int j = 0; j < 8; ++j) {
      const int col = cb + j;
      float v3 = 0.f, v4 = 0.f;
      if (rok && col < kN) {
        float d3 = 0.f, d4 = 0.f;
#pragma unroll
        for (int e = 0; e < 10; ++e) {
          d3 += rreg[e] * s2[e * kN + col];
          d4 += s1[col * 10 + e] * creg[e];
        }
        v3 = __expf(d3) * inv1;
        v4 = __expf(d4) * inv2;
      }
      fo3.h[j] = f2bf(v3);
      fo4.h[j] = f2bf(v4);
    }
    *(uint4*)(arr3 + (size_t)ee * 8) = fo3.q;
    *(uint4*)(arr4 + (size_t)ee * 8) = fo4.q;
  }
}

// ---------------------------------------------------------------------------
// Kernel 2 (r17 = r16 + XCD-aligned block swizzle): FUSED projection +
// dual-softmax attention + adp + Wm.
// r16's h=bx&7 put the 8 same-bt blocks on 8 DIFFERENT XCDs (round-robin
// dispatch) -> each private L2 fetched the bt's 283 KB fp32 input separately
// (FETCH 285 MB, 150 us). r17 decode:
//   r = bx&7; g = bx>>3; h = g&7; bt = (g>>3)*8 + r
// For fixed bt the 8 heads sit at blockIdx r+8h+64*(bt/8): same residue
// mod 8 (SAME XCD), 8 apart in dispatch order (temporally adjacent). Per-XCD
// live set = 8 bts x 283 KB = 2.3 MB < 4 MB L2 -> input fetched once, 7 hits.
// Everything else identical to r16 (verified absmax 2e-3).
// ---------------------------------------------------------------------------
__global__ __launch_bounds__(256, 2) void attn_kernel(
    const float* __restrict__ qin, const float* __restrict__ kin, const float* __restrict__ vin,
    const float* __restrict__ Wq, const float* __restrict__ Wk, const float* __restrict__ Wv,
    const float* __restrict__ bq, const float* __restrict__ bk, const float* __restrict__ bv,
    const u16* __restrict__ arr3, const u16* __restrict__ arr4,
    const float* __restrict__ Wm, const float* __restrict__ bm,
    u16* __restrict__ mg) {
  __shared__ u16 pool[39424];              // 78,848 B
  u16* const s_E   = pool;                 // [192][72]  (13824 elems)
  u16* const s_ET0 = pool + 13824;         // [64][200]  (12800 elems)
  u16* const s_ET1 = pool + 26624;         // [64][200]  (12800 elems)
  u16* const s_q   = pool + 13824;         // alias ET0: [192][24] (4608)
  u16* const s_k   = pool + 18432;         // alias ET0: [192][24] (4608)
  u16* const s_vT  = pool + 23040;         // alias ET0: [16][200] (3200)
  u16* const s_cat = s_ET1;                // alias: 4*1152 = 4608 elems

  const int tid = threadIdx.x;
  // XCD-aligned decode: same-bt blocks share an XCD and are dispatch-adjacent
  const int r8 = blockIdx.x & 7;
  const int g  = blockIdx.x >> 3;
  const int h  = g & 7;
  const int bt = (g >> 3) * 8 + r8;
  const size_t base = (size_t)(h * kBT + bt) * kTile;
  const int w = tid >> 6, lane = tid & 63;
  const int quad = lane >> 4, m = lane & 15;
  const f32x4 zero4 = {0.f, 0.f, 0.f, 0.f};

  // ================= fused projection staging =================
  // wave w computes tiles t = w, w+4, w+8 of each tensor (n0 = t*16).
#pragma unroll
  for (int u = 0; u < 3; ++u) {
    const float* in  = (u == 0) ? qin : (u == 1) ? kin : vin;
    const float* Wt  = (u == 0) ? Wq  : (u == 1) ? Wk  : Wv;
    const float* bs  = (u == 0) ? bq  : (u == 1) ? bk  : bv;
    // W B-frags (lane m = W row h*16+m = output col; quad*8+kp*32 = d)
    bf16x8 wf[4];
#pragma unroll
    for (int kp = 0; kp < 4; ++kp) {
      const float* wp = Wt + (size_t)(h * 16 + m) * 128 + kp * 32 + quad * 8;
      const float4 wa = *(const float4*)wp;
      const float4 wb2 = *(const float4*)(wp + 4);
      FragU f;
      f.q = make_uint4(pack_bf2(wa.x, wa.y), pack_bf2(wa.z, wa.w),
                       pack_bf2(wb2.x, wb2.y), pack_bf2(wb2.z, wb2.w));
      wf[kp] = f.f;
    }
    const float bias = bs[h * 16 + m];
#pragma unroll
    for (int ti = 0; ti < 3; ++ti) {
      const int n0 = (w + ti * 4) * 16;
      f32x4 acc = zero4;
#pragma unroll
      for (int kp = 0; kp < 4; ++kp) {
        FragU a; a.u[0] = 0; a.u[1] = 0;
        const int row = n0 + m;            // A row = input token
        if (row < kN) {
          const float* ap = in + ((size_t)bt * kN + row) * 128 + kp * 32 + quad * 8;
          const float4 xa = *(const float4*)ap;
          const float4 xb = *(const float4*)(ap + 4);
          a.q = make_uint4(pack_bf2(xa.x, xa.y), pack_bf2(xa.z, xa.w),
                           pack_bf2(xb.x, xb.y), pack_bf2(xb.z, xb.w));
        }
        acc = MFMA(a.f, wf[kp], acc);
      }
      // D: lane(m = col c', quad), reg r -> token n0 + quad*4 + r
      if (u == 0) {
#pragma unroll
        for (int r = 0; r < 4; ++r)
          s_q[(n0 + quad * 4 + r) * 24 + m] = f2bf((acc[r] + bias) * KQSCALE);
      } else if (u == 1) {
#pragma unroll
        for (int r = 0; r < 4; ++r)
          s_k[(n0 + quad * 4 + r) * 24 + m] = f2bf(acc[r] + bias);
      } else {
        const int tb = n0 + quad * 4;
        const float v0 = (tb + 0 < kN) ? acc[0] + bias : 0.f;
        const float v1 = (tb + 1 < kN) ? acc[1] + bias : 0.f;
        const float v2 = (tb + 2 < kN) ? acc[2] + bias : 0.f;
        const float v3 = (tb + 3 < kN) ? acc[3] + bias : 0.f;
        uint2 pv;
        pv.x = pack_bf2(v0, v1);
        pv.y = pack_bf2(v2, v3);
        *(uint2*)(s_vT + m * 200 + tb) = pv;   // vT[ch=m][tok tb..tb+3]
      }
    }
  }

  // ---- Wm A-fragments with interleaved cat-dim mapping (unchanged).
  bf16x8 wmb[2];
#pragma unroll
  for (int kt = 0; kt < 2; ++kt) {
    FragU f;
#pragma unroll
    for (int j = 0; j < 8; ++j) {
      const int kdl = quad * 8 + j;
      const int orig = (kt * 2 + (kdl & 1)) * 16 + (kdl >> 1);
      f.h[j] = f2bf(Wm[m * 64 + orig]);
    }
    wmb[kt] = f.f;
  }
  const float4 bm4 = *(const float4*)(bm + quad * 4);

  __syncthreads();   // bar_a: staged q/k/vT visible to all waves

  // ---- K A-frags + Q B-frags from LDS tiles (cross-wave reads).
  bf16x8 kfr[12];
#pragma unroll
  for (int t12 = 0; t12 < 12; ++t12) {
    FragU fk; fk.u[0] = 0; fk.u[1] = 0;
    const int tok = t12 * 16 + m;
    if (quad < 2 && tok < kN)
      fk.q = *(const uint4*)(s_k + tok * 24 + quad * 8);
    kfr[t12] = fk.f;
  }
  bf16x8 qB[3];
#pragma unroll
  for (int ti = 0; ti < 3; ++ti) {
    FragU fq; fq.u[0] = 0; fq.u[1] = 0;
    const int tok = (w + ti * 4) * 16 + m;
    if (quad < 2 && tok < kN)
      fq.q = *(const uint4*)(s_q + tok * 24 + quad * 8);
    qB[ti] = fq.f;
  }
  bf16x8 vb[6];   // V B-frags: B[token][ch]
#pragma unroll
  for (int p = 0; p < 6; ++p) {
    FragU f;
    f.q = *(const uint4*)(s_vT + m * 200 + p * 32 + quad * 8);
    vb[p] = f.f;
  }

  __syncthreads();   // bar_a2: all frag reads done before S0 overwrites ET0

  FragU onesU; onesU.u[0] = 0x3F803F803F803F80ULL; onesU.u[1] = onesU.u[0];
  const bf16x8 ones = onesU.f;

  f32x4 o1[3], l1[3], o3[3], o4[3], o2[3], l2[3];
#pragma unroll
  for (int ti = 0; ti < 3; ++ti) {
    o1[ti] = zero4; l1[ti] = zero4; o3[ti] = zero4;
    o4[ti] = zero4; o2[ti] = zero4; l2[ti] = zero4;
  }

  // S_PHASE(CC, ETB): wave computes its 3 q-tiles x 4 k-tiles of E = exp2(S),
  // stores as b64 into s_E rows (own rows, wave-local) + b16 scatter into ETB.
#define S_PHASE(CC, ETB)                                                      \
  do {                                                                        \
    _Pragma("unroll") for (int ti = 0; ti < 3; ++ti) {                        \
      const int qt = w + ti * 4;                                              \
      const int qrow = qt * 16 + m;                                           \
      _Pragma("unroll") for (int ktl = 0; ktl < 4; ++ktl) {                   \
        f32x4 sv = MFMA(kfr[(CC) * 4 + ktl], qB[ti], zero4);                  \
        const float e0 = exp2f(sv[0]), e1 = exp2f(sv[1]);                     \
        const float e2 = exp2f(sv[2]), e3 = exp2f(sv[3]);                     \
        uint2 ev;                                                             \
        ev.x = pack_trunc(e0, e1);                                            \
        ev.y = pack_trunc(e2, e3);                                            \
        *(uint2*)(s_E + qrow * 72 + ktl * 16 + quad * 4) = ev;                \
        u16* etp = (ETB) + (ktl * 16 + quad * 4) * 200 + qrow;                \
        etp[0]   = trunc_bf(e0);                                              \
        etp[200] = trunc_bf(e1);                                              \
        etp[400] = trunc_bf(e2);                                              \
        etp[600] = trunc_bf(e3);                                              \
      }                                                                       \
    }                                                                         \
  } while (0)

#define LOAD_ARR(CC)                                                          \
  _Pragma("unroll") for (int ti = 0; ti < 3; ++ti) {                          \
    const int qt = w + ti * 4;                                                \
    _Pragma("unroll") for (int pl = 0; pl < 2; ++pl) {                        \
      const int pg = (CC) * 2 + pl;                                           \
      a3f[ti * 2 + pl].q = *(const uint4*)(arr3 + (size_t)((qt * 6 + pg) * 64 + lane) * 8); \
      a4f[ti * 2 + pl].q = *(const uint4*)(arr4 + (size_t)((qt * 6 + pg) * 64 + lane) * 8); \
    }                                                                         \
  }

  // ROW_PHASE(CC): reads own s_E rows (wave-local; no barrier dependency).
#define ROW_PHASE(CC)                                                         \
  _Pragma("unroll") for (int ti = 0; ti < 3; ++ti) {                          \
    const int qt = w + ti * 4;                                                \
    const u16* erp = s_E + (qt * 16 + m) * 72 + quad * 8;                     \
    _Pragma("unroll") for (int pl = 0; pl < 2; ++pl) {                        \
      const int pg = (CC) * 2 + pl;                                           \
      FragU pa; pa.q = *(const uint4*)(erp + pl * 32);                        \
      o1[ti] = MFMA(pa.f, vb[pg], o1[ti]);                                    \
      l1[ti] = MFMA(pa.f, ones, l1[ti]);                                      \
      o3[ti] = MFMA(a3f[ti * 2 + pl].f, vb[pg], o3[ti]);                      \
      o4[ti] = MFMA(a4f[ti * 2 + pl].f, vb[pg], o4[ti]);                      \
    }                                                                         \
  }

  // COL_PHASE(CC, ETB): reads E^T rows (cross-wave; requires barrier).
#define COL_PHASE(CC, ETB)                                                    \
  {                                                                           \
    const u16* etr = (ETB) + (w * 16 + m) * 200 + quad * 8;                   \
    _Pragma("unroll") for (int pg = 0; pg < 6; ++pg) {                        \
      FragU pT; pT.q = *(const uint4*)(etr + pg * 32);                        \
      o2[CC] = MFMA(pT.f, vb[pg], o2[CC]);                                    \
      l2[CC] = MFMA(pT.f, ones, l2[CC]);                                      \
    }                                                                         \
  }

  // ---- I0: produce chunk 0
  S_PHASE(0, s_ET0);
  __syncthreads();   // bar1: ET0 sealed
  // ---- I1: consume chunk 0, produce chunk 1 (ROW reads s_E BEFORE S
  //          overwrites — WAR order)
  {
    FragU a3f[6], a4f[6];
    LOAD_ARR(0);
    COL_PHASE(0, s_ET0);
    ROW_PHASE(0);
    S_PHASE(1, s_ET1);
  }
  __syncthreads();   // bar2: ET1 sealed; COL0 done with ET0
  // ---- I2
  {
    FragU a3f[6], a4f[6];
    LOAD_ARR(1);
    COL_PHASE(1, s_ET1);
    ROW_PHASE(1);
    S_PHASE(2, s_ET0);
  }
  __syncthreads();   // bar3: ET0 sealed; COL1 done with ET1 (cat may reuse)
  // ---- I3
  {
    FragU a3f[6], a4f[6];
    LOAD_ARR(2);
    COL_PHASE(2, s_ET0);
    ROW_PHASE(2);
  }

#undef S_PHASE
#undef LOAD_ARR
#undef ROW_PHASE
#undef COL_PHASE

  // ================= fused Wm epilogue (per own tile) =================
  u16* cw = s_cat + w * 1152;
#pragma unroll
  for (int ti = 0; ti < 3; ++ti) {
    const int tt = w + ti * 4;
#pragma unroll
    for (int r = 0; r < 4; ++r) {
      const int token = quad * 4 + r;
      const float n1 = o1[ti][r] * __builtin_amdgcn_rcpf(l1[ti][r] - 8.0f);
      const float n2 = o2[ti][r] * __builtin_amdgcn_rcpf(l2[ti][r] - 8.0f);
      *(u32*)(cw + token * 72 + 2 * m)      = pack_bf2(n1, n2);       // dims 2m,2m+1
      *(u32*)(cw + token * 72 + 32 + 2 * m) = pack_bf2(o3[ti][r], o4[ti][r]);
    }
    f32x4 macc = {bm4.x, bm4.y, bm4.z, bm4.w};
#pragma unroll
    for (int kt = 0; kt < 2; ++kt) {
      FragU ca; ca.q = *(const uint4*)(cw + m * 72 + kt * 32 + quad * 8);
      macc = MFMA(wmb[kt], ca.f, macc);   // filt^T = Wm @ cat^T
    }
    if (tt * 16 + m < kN) {
      *(uint2*)(mg + base + (tt * 16 + m) * 16 + quad * 4) =
          make_uint2(pack_bf2(macc[0], macc[1]), pack_bf2(macc[2], macc[3]));
    }
  }
}

// ---------------------------------------------------------------------------
// Kernel 3: MFMA head-merge + Wo GEMM, fp32 out + bo (Wo staged from fp32
// with inline RNE conversion).
// ---------------------------------------------------------------------------
__global__ __launch_bounds__(256) void out_kernel(
    const u16* __restrict__ mg, const float* __restrict__ Wo,
    const float* __restrict__ bo, float* __restrict__ outg) {
  __shared__ u16 s_w[128 * 136];
  const int tid = threadIdx.x;
  {
    for (int i = tid; i < 2048; i += 256) {
      const int row = i >> 4, c8 = (i & 15) * 8;
      const float4 w0 = *(const float4*)(Wo + row * 128 + c8);
      const float4 w1 = *(const float4*)(Wo + row * 128 + c8 + 4);
      *(uint4*)(s_w + row * 136 + c8) =
          make_uint4(pack_bf2(w0.x, w0.y), pack_bf2(w0.z, w0.w),
                     pack_bf2(w1.x, w1.y), pack_bf2(w1.z, w1.w));
    }
  }
  __syncthreads();

  const int w = tid >> 6, lane = tid & 63, quad = lane >> 4, m = lane & 15;
  const int r0 = blockIdx.x * 128;

  f32x4 acc0[8], acc1[8];
  const f32x4 z4 = {0.f, 0.f, 0.f, 0.f};
#pragma unroll
  for (int ct = 0; ct < 8; ++ct) { acc0[ct] = z4; acc1[ct] = z4; }

  const int hh = quad >> 1, hd8 = (quad & 1) * 8;
  const int ra = r0 + w * 16 + m;
  const int bt0 = ra / kN, n0 = ra - bt0 * kN;
  const int rb = ra + 64;
  const int bt1 = rb / kN, n1 = rb - bt1 * kN;
  const u16* mp0 = mg + ((size_t)(hh * kBT + bt0) * kN + n0) * 16 + hd8;
  const u16* mp1 = mg + ((size_t)(hh * kBT + bt1) * kN + n1) * 16 + hd8;
  const size_t hstep = (size_t)2 * kBT * kN * 16;

#pragma unroll
  for (int kp = 0; kp < 4; ++kp) {
    FragU a0; a0.q = *(const uint4*)(mp0 + kp * hstep);
    FragU a1; a1.q = *(const uint4*)(mp1 + kp * hstep);
#pragma unroll
    for (int ct = 0; ct < 8; ++ct) {
      FragU bfr; bfr.q = *(const uint4*)(s_w + (ct * 16 + m) * 136 + kp * 32 + quad * 8);
      acc0[ct] = MFMA(a0.f, bfr.f, acc0[ct]);
      acc1[ct] = MFMA(a1.f, bfr.f, acc1[ct]);
    }
  }

  float bc[8];
#pragma unroll
  for (int ct = 0; ct < 8; ++ct) bc[ct] = bo[ct * 16 + m];

#pragma unroll
  for (int half = 0; half < 2; ++half) {
    const f32x4* acc = half ? acc1 : acc0;
    const int rbase = r0 + (w + half * 4) * 16 + quad * 4;
#pragma unroll
    for (int rr = 0; rr < 4; ++rr) {
      float* op = outg + (size_t)(rbase + rr) * 128 + m;
#pragma unroll
      for (int ct = 0; ct < 8; ++ct)
        op[ct * 16] = acc[ct][rr] + bc[ct];
    }
  }
}

// ---------------------------------------------------------------------------
extern "C" void kernel_launch(void* const* d_in, const int* in_sizes, int n_in,
                              void* d_out, int out_size, void* d_ws, size_t ws_size,
                              hipStream_t stream) {
  const float* query = (const float*)d_in[0];
  const float* key   = (const float*)d_in[1];
  const float* value = (const float*)d_in[2];
  const float* Wq = (const float*)d_in[3];
  const float* bq = (const float*)d_in[4];
  const float* Wk = (const float*)d_in[5];
  const float* bk = (const float*)d_in[6];
  const float* Wv = (const float*)d_in[7];
  const float* bv = (const float*)d_in[8];
  const float* Wm = (const float*)d_in[9];
  const float* bm = (const float*)d_in[10];
  const float* Wo = (const float*)d_in[11];
  const float* bo = (const float*)d_in[12];
  const float* ne1 = (const float*)d_in[13];
  const float* ne2 = (const float*)d_in[14];

  const size_t tensor_bytes = (size_t)kH * kB * kT * kN * kHD * 2;  // 12,058,624
  const size_t frag_bytes = (size_t)12 * 6 * 64 * 8 * 2;            // 73,728
  char* ws = (char*)d_ws;
  u16* mgs  = (u16*)(ws);                        // attn output m (bf16)
  u16* arr3 = (u16*)(ws + tensor_bytes);
  u16* arr4 = (u16*)(ws + tensor_bytes + frag_bytes);

  adp_kernel<<<12, 256, 0, stream>>>(ne1, ne2, arr3, arr4);
  attn_kernel<<<kH * kB * kT, 256, 0, stream>>>(
      query, key, value, Wq, Wk, Wv, bq, bk, bv, arr3, arr4, Wm, bm, mgs);
  out_kernel<<<kRows / 128, 256, 0, stream>>>(mgs, Wo, bo, (float*)d_out);
}

// Round 11
// 253.805 us; speedup vs baseline: 1.1537x; 1.1508x over previous
//
#include <hip/hip_runtime.h>

typedef unsigned int u32;
typedef unsigned short u16;
typedef unsigned long long ull;

constexpr int kB = 16, kT = 16, kN = 184, kD = 128, kH = 8, kHD = 16;
constexpr int kBT = kB * kT;            // 256
constexpr int kRows = kBT * kN;         // 47104
constexpr int kTile = kN * kHD;         // 2944 elements per (hb,t) tile
// softmax scale folded into q at projection: 0.25 * log2(e)
#define KQSCALE 0.36067376022224085f

typedef __attribute__((ext_vector_type(8))) short bf16x8;
typedef __attribute__((ext_vector_type(4))) float f32x4;

union FragU {
  bf16x8 f;
  ull u[2];
  uint4 q;
  u16 h[8];
};

#define MFMA(a, b, c) __builtin_amdgcn_mfma_f32_16x16x32_bf16((a), (b), (c), 0, 0, 0)

__device__ __forceinline__ float bf2f(u16 v) {
  return __uint_as_float(((u32)v) << 16);
}
__device__ __forceinline__ u16 f2bf(float f) {
  u32 x = __float_as_uint(f);
  x += 0x7fffu + ((x >> 16) & 1u);   // RNE
  return (u16)(x >> 16);
}
// pack two fp32 -> two bf16 (RNE) in one u32: lo in [15:0], hi in [31:16]
__device__ __forceinline__ u32 pack_bf2(float lo, float hi) {
  u32 a = __float_as_uint(lo); a += 0x7fffu + ((a >> 16) & 1u);
  u32 b = __float_as_uint(hi); b += 0x7fffu + ((b >> 16) & 1u);
  return __builtin_amdgcn_perm(b, a, 0x07060302);
}
// pack two fp32 -> two bf16 (truncate) in one u32 — single v_perm
__device__ __forceinline__ u32 pack_trunc(float lo, float hi) {
  return __builtin_amdgcn_perm(__float_as_uint(hi), __float_as_uint(lo), 0x07060302);
}
__device__ __forceinline__ u16 trunc_bf(float f) {
  return (u16)(__float_as_uint(f) >> 16);
}

// ---------------------------------------------------------------------------
// Kernel 1: adp softmax fragments. Grid 12; phase 1 redundant per block,
// phase 2 block-strided.
// ---------------------------------------------------------------------------
__global__ __launch_bounds__(256) void adp_kernel(
    const float* __restrict__ ne1, const float* __restrict__ ne2,
    u16* __restrict__ arr3, u16* __restrict__ arr4) {
  __shared__ float s1[kN * 10];
  __shared__ float s2[10 * kN];
  __shared__ float l1r[kN];
  __shared__ float l2c[kN];
  const int tid = threadIdx.x;
  for (int i = tid; i < kN * 10; i += 256) { s1[i] = ne1[i]; s2[i] = ne2[i]; }
  __syncthreads();

  if (tid < kN) {
    const int r = tid;
    float reg[10];
#pragma unroll
    for (int e = 0; e < 10; ++e) reg[e] = s1[r * 10 + e];
    float sum = 0.f;
    for (int c = 0; c < kN; ++c) {
      float d = 0.f;
#pragma unroll
      for (int e = 0; e < 10; ++e) d += reg[e] * s2[e * kN + c];
      sum += __expf(d);
    }
    l1r[r] = sum;

    const int c = tid;
    float regc[10];
#pragma unroll
    for (int e = 0; e < 10; ++e) regc[e] = s2[e * kN + c];
    sum = 0.f;
    for (int r2 = 0; r2 < kN; ++r2) {
      float d = 0.f;
#pragma unroll
      for (int e = 0; e < 10; ++e) d += s1[r2 * 10 + e] * regc[e];
      sum += __expf(d);
    }
    l2c[c] = sum;
  }
  __syncthreads();

  for (int ee = blockIdx.x * 256 + tid; ee < 12 * 6 * 64; ee += 12 * 256) {
    const int i = ee / 384;
    const int rem = ee - i * 384;
    const int p = rem >> 6;
    const int lane = rem & 63;
    const int row = i * 16 + (lane & 15);
    const int cb = p * 32 + (lane >> 4) * 8;
    FragU fo3, fo4;
    const bool rok = row < kN;
    float inv1 = 0.f, inv2 = 0.f;
    float rreg[10], creg[10];
    if (rok) {
      inv1 = 1.f / l1r[row];
      inv2 = 1.f / l2c[row];
#pragma unroll
      for (int e = 0; e < 10; ++e) {
        rreg[e] = s1[row * 10 + e];
        creg[e] = s2[e * kN + row];
      }
    }
#pragma unroll
    for (int j = 0; j < 8; ++j) {
      const int col = cb + j;
      float v3 = 0.f, v4 = 0.f;
      if (rok && col < kN) {
        float d3 = 0.f, d4 = 0.f;
#pragma unroll
        for (int e = 0; e < 10; ++e) {
          d3 += rreg[e] * s2[e * kN + col];
          d4 += s1[col * 10 + e] * creg[e];
        }
        v3 = __expf(d3) * inv1;
        v4 = __expf(d4) * inv2;
      }
      fo3.h[j] = f2bf(v3);
      fo4.h[j] = f2bf(v4);
    }
    *(uint4*)(arr3 + (size_t)ee * 8) = fo3.q;
    *(uint4*)(arr4 + (size_t)ee * 8) = fo4.q;
  }
}

// ---------------------------------------------------------------------------
// Kernel 2 (r18 = r17 + coalesced LDS input staging): FUSED projection +
// dual-softmax attention + adp + Wm.
// r17's staging loaded proj A-fragments per-lane from global at 512 B lane
// stride: 64 cache lines per wave-load, 16/64 B used -> ~2.4 GB of L2
// transactions (~70 us). r18 stages each fp32 input tile through LDS with
// COALESCED float4 loads (r12-proj pattern): per tensor u in {q,k,v}:
//   stage in[bt] (184x128 f32) -> s_in[192][136] bf16 (pad rows zeroed)
//   | bar | proj MFMA with A = ds_read_b128 from s_in -> s_q/s_k/s_vT
//   | bar | (s_in reused by next tensor)
// Useful staging traffic: 283 KB/block (~580 MB total, ~17 us of L2 time).
// LDS layout (78,848 B pool, same size — 2 blocks/CU):
//   staging: s_in [0..26112) | s_q [26112..30720) | s_k [30720..35328)
//            | s_vT [35328..38528)
//   attn:    s_E [0..13824) | ET0 [13824..26624) | ET1 [26624..39424)
// Sequencing: all staged regions are consumed into REGISTERS (kfr/qB/vb)
// after the final staging barrier and before bar_a2; S0 (ET0) and S1 (ET1)
// overwrite them only after bar_a2 / bar1. XCD-aligned swizzle kept (r17).
// ---------------------------------------------------------------------------
__global__ __launch_bounds__(256, 2) void attn_kernel(
    const float* __restrict__ qin, const float* __restrict__ kin, const float* __restrict__ vin,
    const float* __restrict__ Wq, const float* __restrict__ Wk, const float* __restrict__ Wv,
    const float* __restrict__ bq, const float* __restrict__ bk, const float* __restrict__ bv,
    const u16* __restrict__ arr3, const u16* __restrict__ arr4,
    const float* __restrict__ Wm, const float* __restrict__ bm,
    u16* __restrict__ mg) {
  __shared__ u16 pool[39424];              // 78,848 B
  u16* const s_E   = pool;                 // [192][72]  (13824 elems)
  u16* const s_ET0 = pool + 13824;         // [64][200]  (12800 elems)
  u16* const s_ET1 = pool + 26624;         // [64][200]  (12800 elems)
  u16* const s_in  = pool;                 // staging: [192][136] (26112)
  u16* const s_q   = pool + 26112;         // staging: [192][24] (4608)
  u16* const s_k   = pool + 30720;         // staging: [192][24] (4608)
  u16* const s_vT  = pool + 35328;         // staging: [16][200] (3200)
  u16* const s_cat = s_ET1;                // epilogue alias: 4*1152

  const int tid = threadIdx.x;
  // XCD-aligned decode: same-bt blocks share an XCD and are dispatch-adjacent
  const int r8 = blockIdx.x & 7;
  const int g  = blockIdx.x >> 3;
  const int h  = g & 7;
  const int bt = (g >> 3) * 8 + r8;
  const int w = tid >> 6, lane = tid & 63;
  const int quad = lane >> 4, m = lane & 15;
  const f32x4 zero4 = {0.f, 0.f, 0.f, 0.f};

  // ================= fused projection staging (coalesced via LDS) =========
#pragma unroll
  for (int u = 0; u < 3; ++u) {
    const float* in  = (u == 0) ? qin : (u == 1) ? kin : vin;
    const float* Wt  = (u == 0) ? Wq  : (u == 1) ? Wk  : Wv;
    const float* bs  = (u == 0) ? bq  : (u == 1) ? bk  : bv;

    // ---- coalesced stage: 23552 floats = 5888 float4, 23 iters of 256
    const float* ibase = in + (size_t)bt * kN * 128;
#pragma unroll
    for (int i = 0; i < 23; ++i) {
      const int idx = (i * 256 + tid) * 4;
      const float4 v4 = *(const float4*)(ibase + idx);
      const int row = idx >> 7, col = idx & 127;
      *(u32*)(s_in + row * 136 + col)     = pack_bf2(v4.x, v4.y);
      *(u32*)(s_in + row * 136 + col + 2) = pack_bf2(v4.z, v4.w);
    }
    // zero pad rows 184..191 (A-frag rows up to 191 are read)
    for (int i = tid; i < 272; i += 256)
      *(ull*)(s_in + 184 * 136 + i * 4) = 0;
    __syncthreads();   // s_in ready

    // ---- W B-frags (lane m = W row h*16+m = output col)
    bf16x8 wf[4];
#pragma unroll
    for (int kp = 0; kp < 4; ++kp) {
      const float* wp = Wt + (size_t)(h * 16 + m) * 128 + kp * 32 + quad * 8;
      const float4 wa = *(const float4*)wp;
      const float4 wb2 = *(const float4*)(wp + 4);
      FragU f;
      f.q = make_uint4(pack_bf2(wa.x, wa.y), pack_bf2(wa.z, wa.w),
                       pack_bf2(wb2.x, wb2.y), pack_bf2(wb2.z, wb2.w));
      wf[kp] = f.f;
    }
    const float bias = bs[h * 16 + m];
#pragma unroll
    for (int ti = 0; ti < 3; ++ti) {
      const int n0 = (w + ti * 4) * 16;
      f32x4 acc = zero4;
#pragma unroll
      for (int kp = 0; kp < 4; ++kp) {
        FragU a; a.q = *(const uint4*)(s_in + (n0 + m) * 136 + kp * 32 + quad * 8);
        acc = MFMA(a.f, wf[kp], acc);
      }
      // D: lane(m = col c', quad), reg r -> token n0 + quad*4 + r
      if (u == 0) {
#pragma unroll
        for (int r = 0; r < 4; ++r)
          s_q[(n0 + quad * 4 + r) * 24 + m] = f2bf((acc[r] + bias) * KQSCALE);
      } else if (u == 1) {
#pragma unroll
        for (int r = 0; r < 4; ++r)
          s_k[(n0 + quad * 4 + r) * 24 + m] = f2bf(acc[r] + bias);
      } else {
        const int tb = n0 + quad * 4;
        const float v0 = (tb + 0 < kN) ? acc[0] + bias : 0.f;
        const float v1 = (tb + 1 < kN) ? acc[1] + bias : 0.f;
        const float v2 = (tb + 2 < kN) ? acc[2] + bias : 0.f;
        const float v3 = (tb + 3 < kN) ? acc[3] + bias : 0.f;
        uint2 pv;
        pv.x = pack_bf2(v0, v1);
        pv.y = pack_bf2(v2, v3);
        *(uint2*)(s_vT + m * 200 + tb) = pv;   // vT[ch=m][tok tb..tb+3]
      }
    }
    __syncthreads();   // proj outputs sealed; s_in free for next tensor
  }

  // ---- Wm A-fragments with interleaved cat-dim mapping (unchanged).
  bf16x8 wmb[2];
#pragma unroll
  for (int kt = 0; kt < 2; ++kt) {
    FragU f;
#pragma unroll
    for (int j = 0; j < 8; ++j) {
      const int kdl = quad * 8 + j;
      const int orig = (kt * 2 + (kdl & 1)) * 16 + (kdl >> 1);
      f.h[j] = f2bf(Wm[m * 64 + orig]);
    }
    wmb[kt] = f.f;
  }
  const float4 bm4 = *(const float4*)(bm + quad * 4);

  // ---- K A-frags + Q B-frags + V B-frags from staged LDS tiles.
  bf16x8 kfr[12];
#pragma unroll
  for (int t12 = 0; t12 < 12; ++t12) {
    FragU fk; fk.u[0] = 0; fk.u[1] = 0;
    const int tok = t12 * 16 + m;
    if (quad < 2 && tok < kN)
      fk.q = *(const uint4*)(s_k + tok * 24 + quad * 8);
    kfr[t12] = fk.f;
  }
  bf16x8 qB[3];
#pragma unroll
  for (int ti = 0; ti < 3; ++ti) {
    FragU fq; fq.u[0] = 0; fq.u[1] = 0;
    const int tok = (w + ti * 4) * 16 + m;
    if (quad < 2 && tok < kN)
      fq.q = *(const uint4*)(s_q + tok * 24 + quad * 8);
    qB[ti] = fq.f;
  }
  bf16x8 vb[6];   // V B-frags: B[token][ch]
#pragma unroll
  for (int p = 0; p < 6; ++p) {
    FragU f;
    f.q = *(const uint4*)(s_vT + m * 200 + p * 32 + quad * 8);
    vb[p] = f.f;
  }

  __syncthreads();   // bar_a2: all frag reads done before S0 overwrites pool

  FragU onesU; onesU.u[0] = 0x3F803F803F803F80ULL; onesU.u[1] = onesU.u[0];
  const bf16x8 ones = onesU.f;

  f32x4 o1[3], l1[3], o3[3], o4[3], o2[3], l2[3];
#pragma unroll
  for (int ti = 0; ti < 3; ++ti) {
    o1[ti] = zero4; l1[ti] = zero4; o3[ti] = zero4;
    o4[ti] = zero4; o2[ti] = zero4; l2[ti] = zero4;
  }

  // S_PHASE(CC, ETB): wave computes its 3 q-tiles x 4 k-tiles of E = exp2(S),
  // stores as b64 into s_E rows (own rows, wave-local) + b16 scatter into ETB.
#define S_PHASE(CC, ETB)                                                      \
  do {                                                                        \
    _Pragma("unroll") for (int ti = 0; ti < 3; ++ti) {                        \
      const int qt = w + ti * 4;                                              \
      const int qrow = qt * 16 + m;                                           \
      _Pragma("unroll") for (int ktl = 0; ktl < 4; ++ktl) {                   \
        f32x4 sv = MFMA(kfr[(CC) * 4 + ktl], qB[ti], zero4);                  \
        const float e0 = exp2f(sv[0]), e1 = exp2f(sv[1]);                     \
        const float e2 = exp2f(sv[2]), e3 = exp2f(sv[3]);                     \
        uint2 ev;                                                             \
        ev.x = pack_trunc(e0, e1);                                            \
        ev.y = pack_trunc(e2, e3);                                            \
        *(uint2*)(s_E + qrow * 72 + ktl * 16 + quad * 4) = ev;                \
        u16* etp = (ETB) + (ktl * 16 + quad * 4) * 200 + qrow;                \
        etp[0]   = trunc_bf(e0);                                              \
        etp[200] = trunc_bf(e1);                                              \
        etp[400] = trunc_bf(e2);                                              \
        etp[600] = trunc_bf(e3);                                              \
      }                                                                       \
    }                                                                         \
  } while (0)

#define LOAD_ARR(CC)                                                          \
  _Pragma("unroll") for (int ti = 0; ti < 3; ++ti) {                          \
    const int qt = w + ti * 4;                                                \
    _Pragma("unroll") for (int pl = 0; pl < 2; ++pl) {                        \
      const int pg = (CC) * 2 + pl;                                           \
      a3f[ti * 2 + pl].q = *(const uint4*)(arr3 + (size_t)((qt * 6 + pg) * 64 + lane) * 8); \
      a4f[ti * 2 + pl].q = *(const uint4*)(arr4 + (size_t)((qt * 6 + pg) * 64 + lane) * 8); \
    }                                                                         \
  }

  // ROW_PHASE(CC): reads own s_E rows (wave-local; no barrier dependency).
#define ROW_PHASE(CC)                                                         \
  _Pragma("unroll") for (int ti = 0; ti < 3; ++ti) {                          \
    const int qt = w + ti * 4;                                                \
    const u16* erp = s_E + (qt * 16 + m) * 72 + quad * 8;                     \
    _Pragma("unroll") for (int pl = 0; pl < 2; ++pl) {                        \
      const int pg = (CC) * 2 + pl;                                           \
      FragU pa; pa.q = *(const uint4*)(erp + pl * 32);                        \
      o1[ti] = MFMA(pa.f, vb[pg], o1[ti]);                                    \
      l1[ti] = MFMA(pa.f, ones, l1[ti]);                                      \
      o3[ti] = MFMA(a3f[ti * 2 + pl].f, vb[pg], o3[ti]);                      \
      o4[ti] = MFMA(a4f[ti * 2 + pl].f, vb[pg], o4[ti]);                      \
    }                                                                         \
  }

  // COL_PHASE(CC, ETB): reads E^T rows (cross-wave; requires barrier).
#define COL_PHASE(CC, ETB)                                                    \
  {                                                                           \
    const u16* etr = (ETB) + (w * 16 + m) * 200 + quad * 8;                   \
    _Pragma("unroll") for (int pg = 0; pg < 6; ++pg) {                        \
      FragU pT; pT.q = *(const uint4*)(etr + pg * 32);                        \
      o2[CC] = MFMA(pT.f, vb[pg], o2[CC]);                                    \
      l2[CC] = MFMA(pT.f, ones, l2[CC]);                                      \
    }                                                                         \
  }

  // ---- I0: produce chunk 0
  S_PHASE(0, s_ET0);
  __syncthreads();   // bar1: ET0 sealed
  // ---- I1: consume chunk 0, produce chunk 1 (ROW reads s_E BEFORE S
  //          overwrites — WAR order)
  {
    FragU a3f[6], a4f[6];
    LOAD_ARR(0);
    COL_PHASE(0, s_ET0);
    ROW_PHASE(0);
    S_PHASE(1, s_ET1);
  }
  __syncthreads();   // bar2: ET1 sealed; COL0 done with ET0
  // ---- I2
  {
    FragU a3f[6], a4f[6];
    LOAD_ARR(1);
    COL_PHASE(1, s_ET1);
    ROW_PHASE(1);
    S_PHASE(2, s_ET0);
  }
  __syncthreads();   // bar3: ET0 sealed; COL1 done with ET1 (cat may reuse)
  // ---- I3
  {
    FragU a3f[6], a4f[6];
    LOAD_ARR(2);
    COL_PHASE(2, s_ET0);
    ROW_PHASE(2);
  }

#undef S_PHASE
#undef LOAD_ARR
#undef ROW_PHASE
#undef COL_PHASE

  // ================= fused Wm epilogue (per own tile) =================
  const size_t base = (size_t)(h * kBT + bt) * kTile;
  u16* cw = s_cat + w * 1152;
#pragma unroll
  for (int ti = 0; ti < 3; ++ti) {
    const int tt = w + ti * 4;
#pragma unroll
    for (int r = 0; r < 4; ++r) {
      const int token = quad * 4 + r;
      const float n1 = o1[ti][r] * __builtin_amdgcn_rcpf(l1[ti][r] - 8.0f);
      const float n2 = o2[ti][r] * __builtin_amdgcn_rcpf(l2[ti][r] - 8.0f);
      *(u32*)(cw + token * 72 + 2 * m)      = pack_bf2(n1, n2);       // dims 2m,2m+1
      *(u32*)(cw + token * 72 + 32 + 2 * m) = pack_bf2(o3[ti][r], o4[ti][r]);
    }
    f32x4 macc = {bm4.x, bm4.y, bm4.z, bm4.w};
#pragma unroll
    for (int kt = 0; kt < 2; ++kt) {
      FragU ca; ca.q = *(const uint4*)(cw + m * 72 + kt * 32 + quad * 8);
      macc = MFMA(wmb[kt], ca.f, macc);   // filt^T = Wm @ cat^T
    }
    if (tt * 16 + m < kN) {
      *(uint2*)(mg + base + (tt * 16 + m) * 16 + quad * 4) =
          make_uint2(pack_bf2(macc[0], macc[1]), pack_bf2(macc[2], macc[3]));
    }
  }
}

// ---------------------------------------------------------------------------
// Kernel 3: MFMA head-merge + Wo GEMM, fp32 out + bo (Wo staged from fp32
// with inline RNE conversion).
// ---------------------------------------------------------------------------
__global__ __launch_bounds__(256) void out_kernel(
    const u16* __restrict__ mg, const float* __restrict__ Wo,
    const float* __restrict__ bo, float* __restrict__ outg) {
  __shared__ u16 s_w[128 * 136];
  const int tid = threadIdx.x;
  {
    for (int i = tid; i < 2048; i += 256) {
      const int row = i >> 4, c8 = (i & 15) * 8;
      const float4 w0 = *(const float4*)(Wo + row * 128 + c8);
      const float4 w1 = *(const float4*)(Wo + row * 128 + c8 + 4);
      *(uint4*)(s_w + row * 136 + c8) =
          make_uint4(pack_bf2(w0.x, w0.y), pack_bf2(w0.z, w0.w),
                     pack_bf2(w1.x, w1.y), pack_bf2(w1.z, w1.w));
    }
  }
  __syncthreads();

  const int w = tid >> 6, lane = tid & 63, quad = lane >> 4, m = lane & 15;
  const int r0 = blockIdx.x * 128;

  f32x4 acc0[8], acc1[8];
  const f32x4 z4 = {0.f, 0.f, 0.f, 0.f};
#pragma unroll
  for (int ct = 0; ct < 8; ++ct) { acc0[ct] = z4; acc1[ct] = z4; }

  const int hh = quad >> 1, hd8 = (quad & 1) * 8;
  const int ra = r0 + w * 16 + m;
  const int bt0 = ra / kN, n0 = ra - bt0 * kN;
  const int rb = ra + 64;
  const int bt1 = rb / kN, n1 = rb - bt1 * kN;
  const u16* mp0 = mg + ((size_t)(hh * kBT + bt0) * kN + n0) * 16 + hd8;
  const u16* mp1 = mg + ((size_t)(hh * kBT + bt1) * kN + n1) * 16 + hd8;
  const size_t hstep = (size_t)2 * kBT * kN * 16;

#pragma unroll
  for (int kp = 0; kp < 4; ++kp) {
    FragU a0; a0.q = *(const uint4*)(mp0 + kp * hstep);
    FragU a1; a1.q = *(const uint4*)(mp1 + kp * hstep);
#pragma unroll
    for (int ct = 0; ct < 8; ++ct) {
      FragU bfr; bfr.q = *(const uint4*)(s_w + (ct * 16 + m) * 136 + kp * 32 + quad * 8);
      acc0[ct] = MFMA(a0.f, bfr.f, acc0[ct]);
      acc1[ct] = MFMA(a1.f, bfr.f, acc1[ct]);
    }
  }

  float bc[8];
#pragma unroll
  for (int ct = 0; ct < 8; ++ct) bc[ct] = bo[ct * 16 + m];

#pragma unroll
  for (int half = 0; half < 2; ++half) {
    const f32x4* acc = half ? acc1 : acc0;
    const int rbase = r0 + (w + half * 4) * 16 + quad * 4;
#pragma unroll
    for (int rr = 0; rr < 4; ++rr) {
      float* op = outg + (size_t)(rbase + rr) * 128 + m;
#pragma unroll
      for (int ct = 0; ct < 8; ++ct)
        op[ct * 16] = acc[ct][rr] + bc[ct];
    }
  }
}

// ---------------------------------------------------------------------------
extern "C" void kernel_launch(void* const* d_in, const int* in_sizes, int n_in,
                              void* d_out, int out_size, void* d_ws, size_t ws_size,
                              hipStream_t stream) {
  const float* query = (const float*)d_in[0];
  const float* key   = (const float*)d_in[1];
  const float* value = (const float*)d_in[2];
  const float* Wq = (const float*)d_in[3];
  const float* bq = (const float*)d_in[4];
  const float* Wk = (const float*)d_in[5];
  const float* bk = (const float*)d_in[6];
  const float* Wv = (const float*)d_in[7];
  const float* bv = (const float*)d_in[8];
  const float* Wm = (const float*)d_in[9];
  const float* bm = (const float*)d_in[10];
  const float* Wo = (const float*)d_in[11];
  const float* bo = (const float*)d_in[12];
  const float* ne1 = (const float*)d_in[13];
  const float* ne2 = (const float*)d_in[14];

  const size_t tensor_bytes = (size_t)kH * kB * kT * kN * kHD * 2;  // 12,058,624
  const size_t frag_bytes = (size_t)12 * 6 * 64 * 8 * 2;            // 73,728
  char* ws = (char*)d_ws;
  u16* mgs  = (u16*)(ws);                        // attn output m (bf16)
  u16* arr3 = (u16*)(ws + tensor_bytes);
  u16* arr4 = (u16*)(ws + tensor_bytes + frag_bytes);

  adp_kernel<<<12, 256, 0, stream>>>(ne1, ne2, arr3, arr4);
  attn_kernel<<<kH * kB * kT, 256, 0, stream>>>(
      query, key, value, Wq, Wk, Wv, bq, bk, bv, arr3, arr4, Wm, bm, mgs);
  out_kernel<<<kRows / 128, 256, 0, stream>>>(mgs, Wo, bo, (float*)d_out);
}

// Round 12
// 217.989 us; speedup vs baseline: 1.3432x; 1.1643x over previous
//
#include <hip/hip_runtime.h>

typedef unsigned int u32;
typedef unsigned short u16;
typedef unsigned long long ull;

constexpr int kB = 16, kT = 16, kN = 184, kD = 128, kH = 8, kHD = 16;
constexpr int kBT = kB * kT;            // 256
constexpr int kRows = kBT * kN;         // 47104
constexpr int kTile = kN * kHD;         // 2944 elements per (hb,t) tile
// softmax scale folded into q at projection: 0.25 * log2(e)
#define KQSCALE 0.36067376022224085f

typedef __attribute__((ext_vector_type(8))) short bf16x8;
typedef __attribute__((ext_vector_type(4))) float f32x4;

union FragU {
  bf16x8 f;
  ull u[2];
  uint4 q;
  u16 h[8];
};

#define MFMA(a, b, c) __builtin_amdgcn_mfma_f32_16x16x32_bf16((a), (b), (c), 0, 0, 0)

__device__ __forceinline__ float bf2f(u16 v) {
  return __uint_as_float(((u32)v) << 16);
}
__device__ __forceinline__ u16 f2bf(float f) {
  u32 x = __float_as_uint(f);
  x += 0x7fffu + ((x >> 16) & 1u);   // RNE
  return (u16)(x >> 16);
}
// pack two fp32 -> two bf16 (RNE) in one u32: lo in [15:0], hi in [31:16]
__device__ __forceinline__ u32 pack_bf2(float lo, float hi) {
  u32 a = __float_as_uint(lo); a += 0x7fffu + ((a >> 16) & 1u);
  u32 b = __float_as_uint(hi); b += 0x7fffu + ((b >> 16) & 1u);
  return __builtin_amdgcn_perm(b, a, 0x07060302);
}
// pack two fp32 -> two bf16 (truncate) in one u32 — single v_perm
__device__ __forceinline__ u32 pack_trunc(float lo, float hi) {
  return __builtin_amdgcn_perm(__float_as_uint(hi), __float_as_uint(lo), 0x07060302);
}
__device__ __forceinline__ u16 trunc_bf(float f) {
  return (u16)(__float_as_uint(f) >> 16);
}

// ---------------------------------------------------------------------------
// Kernel A (merged): blockIdx.y 0..2 = q/k/v projection GEMM (W converted
// fp32->bf16 inline while staging); blockIdx.y == 3, blockIdx.x < 12 = adp
// softmax fragments (concurrent with proj — no data dependency).
// r19: proj epilogue rewritten — accumulators bounce through the dead s_a
// region ([row][136] u16, c = ct*16+m) and are stored as 8 coalesced uint4
// per thread (full 4 KB plane chunks) instead of 64 scalar 2-B stores.
// ---------------------------------------------------------------------------
__global__ __launch_bounds__(256) void proj_kernel(
    const float* __restrict__ qin, const float* __restrict__ kin, const float* __restrict__ vin,
    const float* __restrict__ Wq, const float* __restrict__ Wk, const float* __restrict__ Wv,
    const float* __restrict__ bq, const float* __restrict__ bk, const float* __restrict__ bv,
    u16* __restrict__ qo, u16* __restrict__ ko, u16* __restrict__ vo,
    const float* __restrict__ ne1, const float* __restrict__ ne2,
    u16* __restrict__ arr3, u16* __restrict__ arr4) {
  __shared__ float smem_f[17408];          // 69,632 B pool
  const int tid = threadIdx.x;

  if (blockIdx.y == 3) {
    // ================= adp role (12 blocks) =================
    if (blockIdx.x >= 12) return;
    float* const s1  = smem_f;             // [kN*10]
    float* const s2  = smem_f + 1840;      // [10*kN]
    float* const l1r = smem_f + 3680;      // [kN]
    float* const l2c = smem_f + 3864;      // [kN]

    for (int i = tid; i < kN * 10; i += 256) { s1[i] = ne1[i]; s2[i] = ne2[i]; }
    __syncthreads();

    if (tid < kN) {
      const int r = tid;
      float reg[10];
#pragma unroll
      for (int e = 0; e < 10; ++e) reg[e] = s1[r * 10 + e];
      float sum = 0.f;
      for (int c = 0; c < kN; ++c) {
        float d = 0.f;
#pragma unroll
        for (int e = 0; e < 10; ++e) d += reg[e] * s2[e * kN + c];
        sum += __expf(d);
      }
      l1r[r] = sum;

      const int c = tid;
      float regc[10];
#pragma unroll
      for (int e = 0; e < 10; ++e) regc[e] = s2[e * kN + c];
      sum = 0.f;
      for (int r2 = 0; r2 < kN; ++r2) {
        float d = 0.f;
#pragma unroll
        for (int e = 0; e < 10; ++e) d += s1[r2 * 10 + e] * regc[e];
        sum += __expf(d);
      }
      l2c[c] = sum;
    }
    __syncthreads();

    for (int ee = blockIdx.x * 256 + tid; ee < 12 * 6 * 64; ee += 12 * 256) {
      const int i = ee / 384;
      const int rem = ee - i * 384;
      const int p = rem >> 6;
      const int lane = rem & 63;
      const int row = i * 16 + (lane & 15);
      const int cb = p * 32 + (lane >> 4) * 8;
      FragU fo3, fo4;
      const bool rok = row < kN;
      float inv1 = 0.f, inv2 = 0.f;
      float rreg[10], creg[10];
      if (rok) {
        inv1 = 1.f / l1r[row];
        inv2 = 1.f / l2c[row];
#pragma unroll
        for (int e = 0; e < 10; ++e) {
          rreg[e] = s1[row * 10 + e];
          creg[e] = s2[e * kN + row];
        }
      }
#pragma unroll
      for (int j = 0; j < 8; ++j) {
        const int col = cb + j;
        float v3 = 0.f, v4 = 0.f;
        if (rok && col < kN) {
          float d3 = 0.f, d4 = 0.f;
#pragma unroll
          for (int e = 0; e < 10; ++e) {
            d3 += rreg[e] * s2[e * kN + col];
            d4 += s1[col * 10 + e] * creg[e];
          }
          v3 = __expf(d3) * inv1;
          v4 = __expf(d4) * inv2;
        }
        fo3.h[j] = f2bf(v3);
        fo4.h[j] = f2bf(v4);
      }
      *(uint4*)(arr3 + (size_t)ee * 8) = fo3.q;
      *(uint4*)(arr4 + (size_t)ee * 8) = fo4.q;
    }
    return;
  }

  // ================= projection role =================
  u16* const s_w = (u16*)smem_f;           // [128][136]
  u16* const s_a = (u16*)smem_f + 128 * 136;

  const float* in; const float* Wf; const float* bias; u16* out; float scale;
  if (blockIdx.y == 0)      { in = qin; Wf = Wq; bias = bq; out = qo; scale = KQSCALE; }
  else if (blockIdx.y == 1) { in = kin; Wf = Wk; bias = bk; out = ko; scale = 1.f; }
  else                      { in = vin; Wf = Wv; bias = bv; out = vo; scale = 1.f; }

  const int r0 = blockIdx.x * 128;
  {
    // stage W (fp32 -> bf16 RNE inline; same [row][col8] -> row*136 layout)
    for (int i = tid; i < 2048; i += 256) {
      const int row = i >> 4, c8 = (i & 15) * 8;
      const float4 w0 = *(const float4*)(Wf + row * 128 + c8);
      const float4 w1 = *(const float4*)(Wf + row * 128 + c8 + 4);
      *(uint4*)(s_w + row * 136 + c8) =
          make_uint4(pack_bf2(w0.x, w0.y), pack_bf2(w0.z, w0.w),
                     pack_bf2(w1.x, w1.y), pack_bf2(w1.z, w1.w));
    }
    // stage A-tile (coalesced float4, bf16 RNE)
    const float* abase = in + (size_t)r0 * 128;
#pragma unroll
    for (int i = 0; i < 16; ++i) {
      const int idx = i * 1024 + tid * 4;
      const float4 v = *(const float4*)(abase + idx);
      const int row = idx >> 7, col = idx & 127;
      *(u32*)(s_a + row * 136 + col)     = pack_bf2(v.x, v.y);
      *(u32*)(s_a + row * 136 + col + 2) = pack_bf2(v.z, v.w);
    }
  }
  __syncthreads();

  const int w = tid >> 6, lane = tid & 63, quad = lane >> 4, m = lane & 15;

  f32x4 acc0[8], acc1[8];
  const f32x4 z4 = {0.f, 0.f, 0.f, 0.f};
#pragma unroll
  for (int ct = 0; ct < 8; ++ct) { acc0[ct] = z4; acc1[ct] = z4; }

  const u16* ap0 = s_a + (w * 16 + m) * 136 + quad * 8;
  const u16* ap1 = ap0 + 64 * 136;

#pragma unroll
  for (int kp = 0; kp < 4; ++kp) {
    FragU a0; a0.q = *(const uint4*)(ap0 + kp * 32);
    FragU a1; a1.q = *(const uint4*)(ap1 + kp * 32);
#pragma unroll
    for (int ct = 0; ct < 8; ++ct) {
      FragU bfr; bfr.q = *(const uint4*)(s_w + (ct * 16 + m) * 136 + kp * 32 + quad * 8);
      acc0[ct] = MFMA(a0.f, bfr.f, acc0[ct]);
      acc1[ct] = MFMA(a1.f, bfr.f, acc1[ct]);
    }
  }

  float bc[8];
#pragma unroll
  for (int ct = 0; ct < 8; ++ct) bc[ct] = bias[ct * 16 + m];

  // ---- r19 epilogue: bounce through s_a (dead after MFMA loop), then 8
  // fully-coalesced uint4 stores per thread (4 KB contiguous per plane).
  __syncthreads();   // all waves done reading s_a as A-fragments
#pragma unroll
  for (int half = 0; half < 2; ++half) {
    const f32x4* acc = half ? acc1 : acc0;
    const int rloc = (w + half * 4) * 16 + quad * 4;   // 0..127
#pragma unroll
    for (int rr = 0; rr < 4; ++rr) {
#pragma unroll
      for (int ct = 0; ct < 8; ++ct)
        s_a[(rloc + rr) * 136 + ct * 16 + m] = f2bf((acc[ct][rr] + bc[ct]) * scale);
    }
  }
  __syncthreads();

  const int prow = tid >> 1, phr = (tid & 1) * 8;
#pragma unroll
  for (int ct = 0; ct < 8; ++ct) {
    FragU v; v.q = *(const uint4*)(s_a + prow * 136 + ct * 16 + phr);
    *(uint4*)(out + (size_t)ct * kBT * kN * 16 + (size_t)(r0 + prow) * 16 + phr) = v.q;
  }
}

// ---------------------------------------------------------------------------
// Kernel 3: MFMA dual-softmax attention + adp mixing + fused Wm.
// r11 body verbatim (verified 63 us, absmax 2e-3) + r19: vectorized V
// staging (uint4 global loads instead of 12 scalar 2-B loads per thread).
// ---------------------------------------------------------------------------
__global__ __launch_bounds__(256, 2) void attn_kernel(
    const u16* qg, const u16* __restrict__ kg, const u16* __restrict__ vg,
    const u16* __restrict__ arr3, const u16* __restrict__ arr4,
    const float* __restrict__ Wm, const float* __restrict__ bm,
    u16* mg) {
  __shared__ u16 pool[39424];              // 78848 B total
  u16* const s_E   = pool;                 // [192][72]  (13824 elems)
  u16* const s_ET0 = pool + 13824;         // [64][200]  (12800 elems)
  u16* const s_ET1 = pool + 26624;         // [64][200]  (12800 elems)
  u16* const s_vT  = s_ET1;                // alias: [16][200] (3200 elems)
  u16* const s_cat = s_ET1;                // alias: 4*1152 = 4608 elems

  const int tid = threadIdx.x;
  const size_t base = (size_t)blockIdx.x * kTile;
  const int w = tid >> 6, lane = tid & 63;
  const int quad = lane >> 4, m = lane & 15;

  // ---- stage V transposed into s_vT (vectorized: 384 uint4 reads)
  for (int i = tid; i < 384; i += 256) {
    const int t = i >> 1, c8 = (i & 1) * 8;
    FragU f;
    if (t < kN) f.q = *(const uint4*)(vg + base + t * 16 + c8);
    else { f.u[0] = 0; f.u[1] = 0; }
#pragma unroll
    for (int j = 0; j < 8; ++j) s_vT[(c8 + j) * 200 + t] = f.h[j];
  }

  // ---- K A-fragments (rows = k tokens) for ALL 12 k-tiles, from global.
  bf16x8 kfr[12];
#pragma unroll
  for (int t12 = 0; t12 < 12; ++t12) {
    FragU fk; fk.u[0] = 0; fk.u[1] = 0;
    const int tok = t12 * 16 + m;
    if (quad < 2 && tok < kN)
      fk.q = *(const uint4*)(kg + base + tok * 16 + quad * 8);
    kfr[t12] = fk.f;
  }
  // ---- Q B-fragments for this wave's own 3 q-tiles {w, w+4, w+8}.
  bf16x8 qB[3];
#pragma unroll
  for (int ti = 0; ti < 3; ++ti) {
    FragU fq; fq.u[0] = 0; fq.u[1] = 0;
    const int tok = (w + ti * 4) * 16 + m;
    if (quad < 2 && tok < kN)
      fq.q = *(const uint4*)(qg + base + tok * 16 + quad * 8);
    qB[ti] = fq.f;
  }

  // ---- Wm A-fragments with interleaved cat-dim mapping (unchanged).
  bf16x8 wmb[2];
#pragma unroll
  for (int kt = 0; kt < 2; ++kt) {
    FragU f;
#pragma unroll
    for (int j = 0; j < 8; ++j) {
      const int kdl = quad * 8 + j;
      const int orig = (kt * 2 + (kdl & 1)) * 16 + (kdl >> 1);
      f.h[j] = f2bf(Wm[m * 64 + orig]);
    }
    wmb[kt] = f.f;
  }
  const float4 bm4 = *(const float4*)(bm + quad * 4);

  // bar_a: s_vT ready AND all waves' qg reads drained (mg aliases qg; mg
  // writes happen only after bar3).
  __syncthreads();

  bf16x8 vb[6];   // V B-frags: B[token][ch]
#pragma unroll
  for (int p = 0; p < 6; ++p) {
    FragU f;
    f.q = *(const uint4*)(s_vT + m * 200 + p * 32 + quad * 8);
    vb[p] = f.f;
  }
  FragU onesU; onesU.u[0] = 0x3F803F803F803F80ULL; onesU.u[1] = onesU.u[0];
  const bf16x8 ones = onesU.f;
  const f32x4 zero4 = {0.f, 0.f, 0.f, 0.f};

  f32x4 o1[3], l1[3], o3[3], o4[3], o2[3], l2[3];
#pragma unroll
  for (int ti = 0; ti < 3; ++ti) {
    o1[ti] = zero4; l1[ti] = zero4; o3[ti] = zero4;
    o4[ti] = zero4; o2[ti] = zero4; l2[ti] = zero4;
  }

  // S_PHASE(CC, ETB): wave computes its 3 q-tiles x 4 k-tiles of E = exp2(S),
  // stores as b64 into s_E rows (own rows, wave-local) + b16 scatter into ETB.
#define S_PHASE(CC, ETB)                                                      \
  do {                                                                        \
    _Pragma("unroll") for (int ti = 0; ti < 3; ++ti) {                        \
      const int qt = w + ti * 4;                                              \
      const int qrow = qt * 16 + m;                                           \
      _Pragma("unroll") for (int ktl = 0; ktl < 4; ++ktl) {                   \
        f32x4 sv = MFMA(kfr[(CC) * 4 + ktl], qB[ti], zero4);                  \
        const float e0 = exp2f(sv[0]), e1 = exp2f(sv[1]);                     \
        const float e2 = exp2f(sv[2]), e3 = exp2f(sv[3]);                     \
        uint2 ev;                                                             \
        ev.x = pack_trunc(e0, e1);                                            \
        ev.y = pack_trunc(e2, e3);                                            \
        *(uint2*)(s_E + qrow * 72 + ktl * 16 + quad * 4) = ev;                \
        u16* etp = (ETB) + (ktl * 16 + quad * 4) * 200 + qrow;                \
        etp[0]   = trunc_bf(e0);                                              \
        etp[200] = trunc_bf(e1);                                              \
        etp[400] = trunc_bf(e2);                                              \
        etp[600] = trunc_bf(e3);                                              \
      }                                                                       \
    }                                                                         \
  } while (0)

#define LOAD_ARR(CC)                                                          \
  _Pragma("unroll") for (int ti = 0; ti < 3; ++ti) {                          \
    const int qt = w + ti * 4;                                                \
    _Pragma("unroll") for (int pl = 0; pl < 2; ++pl) {                        \
      const int pg = (CC) * 2 + pl;                                           \
      a3f[ti * 2 + pl].q = *(const uint4*)(arr3 + (size_t)((qt * 6 + pg) * 64 + lane) * 8); \
      a4f[ti * 2 + pl].q = *(const uint4*)(arr4 + (size_t)((qt * 6 + pg) * 64 + lane) * 8); \
    }                                                                         \
  }

  // ROW_PHASE(CC): reads own s_E rows (wave-local; no barrier dependency).
#define ROW_PHASE(CC)                                                         \
  _Pragma("unroll") for (int ti = 0; ti < 3; ++ti) {                          \
    const int qt = w + ti * 4;                                                \
    const u16* erp = s_E + (qt * 16 + m) * 72 + quad * 8;                     \
    _Pragma("unroll") for (int pl = 0; pl < 2; ++pl) {                        \
      const int pg = (CC) * 2 + pl;                                           \
      FragU pa; pa.q = *(const uint4*)(erp + pl * 32);                        \
      o1[ti] = MFMA(pa.f, vb[pg], o1[ti]);                                    \
      l1[ti] = MFMA(pa.f, ones, l1[ti]);                                      \
      o3[ti] = MFMA(a3f[ti * 2 + pl].f, vb[pg], o3[ti]);                      \
      o4[ti] = MFMA(a4f[ti * 2 + pl].f, vb[pg], o4[ti]);                      \
    }                                                                         \
  }

  // COL_PHASE(CC, ETB): reads E^T rows (cross-wave; requires barrier).
#define COL_PHASE(CC, ETB)                                                    \
  {                                                                           \
    const u16* etr = (ETB) + (w * 16 + m) * 200 + quad * 8;                   \
    _Pragma("unroll") for (int pg = 0; pg < 6; ++pg) {                        \
      FragU pT; pT.q = *(const uint4*)(etr + pg * 32);                        \
      o2[CC] = MFMA(pT.f, vb[pg], o2[CC]);                                    \
      l2[CC] = MFMA(pT.f, ones, l2[CC]);                                      \
    }                                                                         \
  }

  // ---- I0: produce chunk 0
  S_PHASE(0, s_ET0);
  __syncthreads();   // bar1: ET0 sealed; vb reads sealed before S1 hits ET1
  // ---- I1: consume chunk 0, produce chunk 1 (ROW0 reads s_E BEFORE S1
  //          overwrites it — WAR order)
  {
    FragU a3f[6], a4f[6];
    LOAD_ARR(0);
    COL_PHASE(0, s_ET0);
    ROW_PHASE(0);
    S_PHASE(1, s_ET1);
  }
  __syncthreads();   // bar2: ET1 sealed; COL0 done with ET0
  // ---- I2
  {
    FragU a3f[6], a4f[6];
    LOAD_ARR(1);
    COL_PHASE(1, s_ET1);
    ROW_PHASE(1);
    S_PHASE(2, s_ET0);
  }
  __syncthreads();   // bar3: ET0 sealed; COL1 done with ET1 (cat may reuse)
  // ---- I3
  {
    FragU a3f[6], a4f[6];
    LOAD_ARR(2);
    COL_PHASE(2, s_ET0);
    ROW_PHASE(2);
  }

#undef S_PHASE
#undef LOAD_ARR
#undef ROW_PHASE
#undef COL_PHASE

  // ================= fused Wm epilogue (per own tile) =================
  u16* cw = s_cat + w * 1152;
#pragma unroll
  for (int ti = 0; ti < 3; ++ti) {
    const int tt = w + ti * 4;
#pragma unroll
    for (int r = 0; r < 4; ++r) {
      const int token = quad * 4 + r;
      const float n1 = o1[ti][r] * __builtin_amdgcn_rcpf(l1[ti][r] - 8.0f);
      const float n2 = o2[ti][r] * __builtin_amdgcn_rcpf(l2[ti][r] - 8.0f);
      *(u32*)(cw + token * 72 + 2 * m)      = pack_bf2(n1, n2);       // dims 2m,2m+1
      *(u32*)(cw + token * 72 + 32 + 2 * m) = pack_bf2(o3[ti][r], o4[ti][r]);
    }
    f32x4 macc = {bm4.x, bm4.y, bm4.z, bm4.w};
#pragma unroll
    for (int kt = 0; kt < 2; ++kt) {
      FragU ca; ca.q = *(const uint4*)(cw + m * 72 + kt * 32 + quad * 8);
      macc = MFMA(wmb[kt], ca.f, macc);   // filt^T = Wm @ cat^T
    }
    if (tt * 16 + m < kN) {
      *(uint2*)(mg + base + (tt * 16 + m) * 16 + quad * 4) =
          make_uint2(pack_bf2(macc[0], macc[1]), pack_bf2(macc[2], macc[3]));
    }
  }
}

// ---------------------------------------------------------------------------
// Kernel 4: MFMA head-merge + Wo GEMM, fp32 out + bo (Wo staged from fp32
// with inline RNE conversion — unchanged).
// ---------------------------------------------------------------------------
__global__ __launch_bounds__(256) void out_kernel(
    const u16* __restrict__ mg, const float* __restrict__ Wo,
    const float* __restrict__ bo, float* __restrict__ outg) {
  __shared__ u16 s_w[128 * 136];
  const int tid = threadIdx.x;
  {
    for (int i = tid; i < 2048; i += 256) {
      const int row = i >> 4, c8 = (i & 15) * 8;
      const float4 w0 = *(const float4*)(Wo + row * 128 + c8);
      const float4 w1 = *(const float4*)(Wo + row * 128 + c8 + 4);
      *(uint4*)(s_w + row * 136 + c8) =
          make_uint4(pack_bf2(w0.x, w0.y), pack_bf2(w0.z, w0.w),
                     pack_bf2(w1.x, w1.y), pack_bf2(w1.z, w1.w));
    }
  }
  __syncthreads();

  const int w = tid >> 6, lane = tid & 63, quad = lane >> 4, m = lane & 15;
  const int r0 = blockIdx.x * 128;

  f32x4 acc0[8], acc1[8];
  const f32x4 z4 = {0.f, 0.f, 0.f, 0.f};
#pragma unroll
  for (int ct = 0; ct < 8; ++ct) { acc0[ct] = z4; acc1[ct] = z4; }

  const int hh = quad >> 1, hd8 = (quad & 1) * 8;
  const int ra = r0 + w * 16 + m;
  const int bt0 = ra / kN, n0 = ra - bt0 * kN;
  const int rb = ra + 64;
  const int bt1 = rb / kN, n1 = rb - bt1 * kN;
  const u16* mp0 = mg + ((size_t)(hh * kBT + bt0) * kN + n0) * 16 + hd8;
  const u16* mp1 = mg + ((size_t)(hh * kBT + bt1) * kN + n1) * 16 + hd8;
  const size_t hstep = (size_t)2 * kBT * kN * 16;

#pragma unroll
  for (int kp = 0; kp < 4; ++kp) {
    FragU a0; a0.q = *(const uint4*)(mp0 + kp * hstep);
    FragU a1; a1.q = *(const uint4*)(mp1 + kp * hstep);
#pragma unroll
    for (int ct = 0; ct < 8; ++ct) {
      FragU bfr; bfr.q = *(const uint4*)(s_w + (ct * 16 + m) * 136 + kp * 32 + quad * 8);
      acc0[ct] = MFMA(a0.f, bfr.f, acc0[ct]);
      acc1[ct] = MFMA(a1.f, bfr.f, acc1[ct]);
    }
  }

  float bc[8];
#pragma unroll
  for (int ct = 0; ct < 8; ++ct) bc[ct] = bo[ct * 16 + m];

#pragma unroll
  for (int half = 0; half < 2; ++half) {
    const f32x4* acc = half ? acc1 : acc0;
    const int rbase = r0 + (w + half * 4) * 16 + quad * 4;
#pragma unroll
    for (int rr = 0; rr < 4; ++rr) {
      float* op = outg + (size_t)(rbase + rr) * 128 + m;
#pragma unroll
      for (int ct = 0; ct < 8; ++ct)
        op[ct * 16] = acc[ct][rr] + bc[ct];
    }
  }
}

// ---------------------------------------------------------------------------
extern "C" void kernel_launch(void* const* d_in, const int* in_sizes, int n_in,
                              void* d_out, int out_size, void* d_ws, size_t ws_size,
                              hipStream_t stream) {
  const float* query = (const float*)d_in[0];
  const float* key   = (const float*)d_in[1];
  const float* value = (const float*)d_in[2];
  const float* Wq = (const float*)d_in[3];
  const float* bq = (const float*)d_in[4];
  const float* Wk = (const float*)d_in[5];
  const float* bk = (const float*)d_in[6];
  const float* Wv = (const float*)d_in[7];
  const float* bv = (const float*)d_in[8];
  const float* Wm = (const float*)d_in[9];
  const float* bm = (const float*)d_in[10];
  const float* Wo = (const float*)d_in[11];
  const float* bo = (const float*)d_in[12];
  const float* ne1 = (const float*)d_in[13];
  const float* ne2 = (const float*)d_in[14];

  const size_t tensor_bytes = (size_t)kH * kB * kT * kN * kHD * 2;  // 12,058,624
  const size_t frag_bytes = (size_t)12 * 6 * 64 * 8 * 2;            // 73,728
  char* ws = (char*)d_ws;
  u16* qs   = (u16*)(ws);                        // reused as m after attn
  u16* ks   = (u16*)(ws + tensor_bytes);
  u16* vs   = (u16*)(ws + 2 * tensor_bytes);
  u16* arr3 = (u16*)(ws + 3 * tensor_bytes);
  u16* arr4 = (u16*)(ws + 3 * tensor_bytes + frag_bytes);

  proj_kernel<<<dim3(kRows / 128, 4), 256, 0, stream>>>(
      query, key, value, Wq, Wk, Wv, bq, bk, bv, qs, ks, vs,
      ne1, ne2, arr3, arr4);
  attn_kernel<<<kH * kB * kT, 256, 0, stream>>>(qs, ks, vs, arr3, arr4, Wm, bm, qs);
  out_kernel<<<kRows / 128, 256, 0, stream>>>(qs, Wo, bo, (float*)d_out);
}